// Round 1
// baseline (2193.023 us; speedup 1.0000x reference)
//
#include <hip/hip_runtime.h>
#include <math.h>

// ---------------- conv1: [512,4,84,84] * [32,4,8,8] s4 -> relu -> [512,32,20,20]
__global__ __launch_bounds__(256) void conv1_k(const float* __restrict__ x,
                                               const float* __restrict__ w,
                                               const float* __restrict__ bias,
                                               float* __restrict__ y) {
    __shared__ float ws[32 * 4 * 8 * 8];  // 8192 floats = 32 KB
    const int tid = threadIdx.x;
    for (int i = tid; i < 8192; i += 256) ws[i] = w[i];
    __syncthreads();

    const int idx = blockIdx.x * 256 + tid;  // total 6,553,600 = 25600*256
    const int ow = idx % 20;
    int t = idx / 20;
    const int oh = t % 20; t /= 20;
    const int oc = t % 32;
    const int b  = t / 32;

    float acc = bias[oc];
    const float* xb = x + (size_t)b * 4 * 84 * 84;
    #pragma unroll
    for (int ic = 0; ic < 4; ++ic) {
        const float* xc = xb + ic * 84 * 84;
        #pragma unroll
        for (int kh = 0; kh < 8; ++kh) {
            const int ih = oh * 4 + kh;
            const float4* xr = (const float4*)(xc + ih * 84 + ow * 4);  // 16B aligned
            const float4 x0 = xr[0], x1 = xr[1];
            const float4* wr = (const float4*)(ws + ((oc * 4 + ic) * 8 + kh) * 8);
            const float4 w0 = wr[0], w1 = wr[1];
            acc += x0.x * w0.x + x0.y * w0.y + x0.z * w0.z + x0.w * w0.w
                 + x1.x * w1.x + x1.y * w1.y + x1.z * w1.z + x1.w * w1.w;
        }
    }
    y[idx] = fmaxf(acc, 0.f);
}

// ---------------- conv2: [512,32,20,20] * [64,32,4,4] s2 -> relu -> [512,64,9,9]
__global__ __launch_bounds__(256) void conv2_k(const float* __restrict__ x,
                                               const float* __restrict__ w,
                                               const float* __restrict__ bias,
                                               float* __restrict__ y) {
    const int idx = blockIdx.x * 256 + threadIdx.x;  // total 2,654,208 = 10368*256
    const int ow = idx % 9;
    int t = idx / 9;
    const int oh = t % 9; t /= 9;
    const int oc = t % 64;
    const int b  = t / 64;

    float acc = bias[oc];
    const float* xb = x + (size_t)b * 32 * 400;
    const float* wb = w + oc * 32 * 16;
    for (int ic = 0; ic < 32; ++ic) {
        const float* xc = xb + ic * 400 + (oh * 2) * 20 + ow * 2;
        const float* wc = wb + ic * 16;
        #pragma unroll
        for (int kh = 0; kh < 4; ++kh) {
            const float2* xr = (const float2*)(xc + kh * 20);  // 8B aligned
            const float2 xa = xr[0], xc2 = xr[1];
            const float4 wv = *(const float4*)(wc + kh * 4);
            acc += xa.x * wv.x + xa.y * wv.y + xc2.x * wv.z + xc2.y * wv.w;
        }
    }
    y[idx] = fmaxf(acc, 0.f);
}

// ---------------- conv3: [512,64,9,9] * [64,64,3,3] s1 -> relu -> [512,64,7,7]
__global__ __launch_bounds__(256) void conv3_k(const float* __restrict__ x,
                                               const float* __restrict__ w,
                                               const float* __restrict__ bias,
                                               float* __restrict__ y) {
    const int idx = blockIdx.x * 256 + threadIdx.x;  // total 1,605,632 = 6272*256
    const int ow = idx % 7;
    int t = idx / 7;
    const int oh = t % 7; t /= 7;
    const int oc = t % 64;
    const int b  = t / 64;

    float acc = bias[oc];
    const float* xb = x + (size_t)b * 64 * 81;
    const float* wb = w + oc * 64 * 9;
    for (int ic = 0; ic < 64; ++ic) {
        const float* xc = xb + ic * 81 + oh * 9 + ow;
        const float* wc = wb + ic * 9;
        #pragma unroll
        for (int kh = 0; kh < 3; ++kh) {
            acc += xc[kh * 9 + 0] * wc[kh * 3 + 0]
                 + xc[kh * 9 + 1] * wc[kh * 3 + 1]
                 + xc[kh * 9 + 2] * wc[kh * 3 + 2];
        }
    }
    y[idx] = fmaxf(acc, 0.f);
}

// ---------------- fc: [512,3136] @ [3136,256] + b -> relu -> [512,256]; 4 rows/block
__global__ __launch_bounds__(256) void fc_k(const float* __restrict__ a,
                                            const float* __restrict__ w,
                                            const float* __restrict__ bias,
                                            float* __restrict__ out) {
    __shared__ float lin[4 * 3136];  // 49 KB
    const int tid = threadIdx.x;
    const int b0 = blockIdx.x * 4;
    for (int i = tid; i < 4 * 3136; i += 256) lin[i] = a[(size_t)b0 * 3136 + i];
    __syncthreads();

    float acc0 = bias[tid], acc1 = acc0, acc2 = acc0, acc3 = acc0;
    const float* wp = w + tid;
    #pragma unroll 4
    for (int k = 0; k < 3136; ++k) {
        const float wv = wp[(size_t)k * 256];
        acc0 += lin[k] * wv;
        acc1 += lin[3136 + k] * wv;
        acc2 += lin[2 * 3136 + k] * wv;
        acc3 += lin[3 * 3136 + k] * wv;
    }
    out[(b0 + 0) * 256 + tid] = fmaxf(acc0, 0.f);
    out[(b0 + 1) * 256 + tid] = fmaxf(acc1, 0.f);
    out[(b0 + 2) * 256 + tid] = fmaxf(acc2, 0.f);
    out[(b0 + 3) * 256 + tid] = fmaxf(acc3, 0.f);
}

// ---------------- dense 256->256 (+relu): block per row
__global__ __launch_bounds__(256) void dense256_relu_k(const float* __restrict__ in,
                                                       const float* __restrict__ w,
                                                       const float* __restrict__ bias,
                                                       float* __restrict__ out) {
    __shared__ float lin[256];
    const int b = blockIdx.x, tid = threadIdx.x;
    lin[tid] = in[b * 256 + tid];
    __syncthreads();
    float acc = bias[tid];
    #pragma unroll 8
    for (int k = 0; k < 256; ++k) acc += lin[k] * w[k * 256 + tid];
    out[b * 256 + tid] = fmaxf(acc, 0.f);
}

// ---------------- dense 256->64 (no relu): 4 rows/block
__global__ __launch_bounds__(256) void dense64_k(const float* __restrict__ in,
                                                 const float* __restrict__ w,
                                                 const float* __restrict__ bias,
                                                 float* __restrict__ out) {
    __shared__ float lin[4 * 256];
    const int tid = threadIdx.x;
    const int b0 = blockIdx.x * 4;
    for (int i = tid; i < 1024; i += 256) lin[i] = in[b0 * 256 + i];
    __syncthreads();
    const int r = tid >> 6, n = tid & 63;
    float acc = bias[n];
    #pragma unroll 8
    for (int k = 0; k < 256; ++k) acc += lin[r * 256 + k] * w[k * 64 + n];
    out[(b0 + r) * 64 + n] = acc;
}

// ---------------- dense 256->1 (no relu): one wave per row
__global__ __launch_bounds__(64) void dense1_k(const float* __restrict__ in,
                                               const float* __restrict__ w,
                                               const float* __restrict__ bias,
                                               float* __restrict__ out) {
    const int b = blockIdx.x, l = threadIdx.x;
    const float4 hv = *(const float4*)(in + b * 256 + l * 4);
    const float4 wv = *(const float4*)(w + l * 4);
    float p = hv.x * wv.x + hv.y * wv.y + hv.z * wv.z + hv.w * wv.w;
    #pragma unroll
    for (int off = 32; off > 0; off >>= 1) p += __shfl_down(p, off);
    if (l == 0) out[b] = p + bias[0];
}

// ---------------- transpose phi_y [512,64] -> [64,512]
__global__ __launch_bounds__(256) void transpose_phi_k(const float* __restrict__ phi,
                                                       float* __restrict__ phiT) {
    const int idx = blockIdx.x * 256 + threadIdx.x;  // 32768
    const int j = idx >> 6, k = idx & 63;
    phiT[k * 512 + j] = phi[idx];
}

// ---------------- per-row logits + logsumexp + diag
__global__ __launch_bounds__(256) void row_lse_k(const float* __restrict__ phi_x,
                                                 const float* __restrict__ phiYT,
                                                 const float* __restrict__ c_y,
                                                 float* __restrict__ row_lse,
                                                 float* __restrict__ row_diag) {
    const int i = blockIdx.x, tid = threadIdx.x;
    __shared__ float px[64];
    __shared__ float red[256];
    if (tid < 64) px[tid] = phi_x[i * 64 + tid];
    __syncthreads();

    float lg[2];
    #pragma unroll
    for (int q = 0; q < 2; ++q) {
        const int j = tid + q * 256;
        float m = -1e30f;
        #pragma unroll 8
        for (int k = 0; k < 32; ++k) m = fmaxf(m, px[k] - phiYT[k * 512 + j]);
        const float maxc = fmaxf(m, 0.f);
        float s = 0.f;
        #pragma unroll 8
        for (int k = 32; k < 64; ++k) {
            const float d = px[k] - phiYT[k * 512 + j];
            s += d * d;
        }
        lg[q] = c_y[j] - (maxc + sqrtf(s + 1e-8f));
    }
    if ((i & 255) == tid) row_diag[i] = lg[i >> 8];

    red[tid] = fmaxf(lg[0], lg[1]);
    __syncthreads();
    for (int s = 128; s > 0; s >>= 1) {
        if (tid < s) red[tid] = fmaxf(red[tid], red[tid + s]);
        __syncthreads();
    }
    const float m = red[0];
    __syncthreads();
    red[tid] = expf(lg[0] - m) + expf(lg[1] - m);
    __syncthreads();
    for (int s = 128; s > 0; s >>= 1) {
        if (tid < s) red[tid] += red[tid + s];
        __syncthreads();
    }
    if (tid == 0) row_lse[i] = m + logf(red[0]);
}

// ---------------- final scalar loss
__global__ __launch_bounds__(512) void loss_k(const float* __restrict__ row_lse,
                                              const float* __restrict__ row_diag,
                                              float* __restrict__ out) {
    __shared__ float r1[512], r2[512];
    const int t = threadIdx.x;
    const float lse = row_lse[t], dg = row_diag[t];
    r1[t] = lse - dg;                 // -(diag log_softmax)
    const float l = lse + 1e-6f;      // logsumexp(logits + 1e-6)
    r2[t] = l * l;
    __syncthreads();
    for (int s = 256; s > 0; s >>= 1) {
        if (t < s) { r1[t] += r1[t + s]; r2[t] += r2[t + s]; }
        __syncthreads();
    }
    if (t == 0) out[0] = r1[0] / 512.f + 0.1f * (r2[0] / 512.f);
}

extern "C" void kernel_launch(void* const* d_in, const int* in_sizes, int n_in,
                              void* d_out, int out_size, void* d_ws, size_t ws_size,
                              hipStream_t stream) {
    const float* curr = (const float*)d_in[0];
    const float* nxt  = (const float*)d_in[1];
    const float* c1w  = (const float*)d_in[2];
    const float* c1b  = (const float*)d_in[3];
    const float* c2w  = (const float*)d_in[4];
    const float* c2b  = (const float*)d_in[5];
    const float* c3w  = (const float*)d_in[6];
    const float* c3b  = (const float*)d_in[7];
    const float* fcw  = (const float*)d_in[8];
    const float* fcb  = (const float*)d_in[9];
    const float* e1w  = (const float*)d_in[10];
    const float* e1b  = (const float*)d_in[11];
    const float* e2w  = (const float*)d_in[12];
    const float* e2b  = (const float*)d_in[13];
    const float* pw1  = (const float*)d_in[14];
    const float* pb1  = (const float*)d_in[15];
    const float* pw2  = (const float*)d_in[16];
    const float* pb2  = (const float*)d_in[17];

    float* ws = (float*)d_ws;
    float* a1      = ws;                   // 512*32*400  = 6,553,600
    float* a2      = a1 + 6553600;         // 512*64*81   = 2,654,208
    float* a3      = a2 + 2654208;         // 512*64*49   = 1,605,632
    float* feat_c  = a3 + 1605632;         // 131072
    float* feat_n  = feat_c + 131072;      // 131072
    float* h1      = feat_n + 131072;      // 131072
    float* phi_x   = h1 + 131072;          // 32768
    float* phi_y   = phi_x + 32768;        // 32768
    float* phiYT   = phi_y + 32768;        // 32768
    float* c_y     = phiYT + 32768;        // 512
    float* rlse    = c_y + 512;            // 512
    float* rdiag   = rlse + 512;           // 512
    // total ~11.3M floats ~= 45.3 MB

    for (int pass = 0; pass < 2; ++pass) {
        const float* obs = pass ? nxt : curr;
        float* feat = pass ? feat_n : feat_c;
        conv1_k<<<25600, 256, 0, stream>>>(obs, c1w, c1b, a1);
        conv2_k<<<10368, 256, 0, stream>>>(a1, c2w, c2b, a2);
        conv3_k<<<6272, 256, 0, stream>>>(a2, c3w, c3b, a3);
        fc_k<<<128, 256, 0, stream>>>(a3, fcw, fcb, feat);
    }

    dense256_relu_k<<<512, 256, 0, stream>>>(feat_c, e1w, e1b, h1);
    dense64_k<<<128, 256, 0, stream>>>(h1, e2w, e2b, phi_x);
    dense256_relu_k<<<512, 256, 0, stream>>>(feat_n, e1w, e1b, h1);
    dense64_k<<<128, 256, 0, stream>>>(h1, e2w, e2b, phi_y);
    dense256_relu_k<<<512, 256, 0, stream>>>(feat_n, pw1, pb1, h1);
    dense1_k<<<512, 64, 0, stream>>>(h1, pw2, pb2, c_y);

    transpose_phi_k<<<128, 256, 0, stream>>>(phi_y, phiYT);
    row_lse_k<<<512, 256, 0, stream>>>(phi_x, phiYT, c_y, rlse, rdiag);
    loss_k<<<1, 512, 0, stream>>>(rlse, rdiag, (float*)d_out);
}

// Round 2
// 859.336 us; speedup vs baseline: 2.5520x; 2.5520x over previous
//
#include <hip/hip_runtime.h>
#include <math.h>

// ---------------- conv1 tiled: [512,4,84,84] * [32,4,8,8] s4 -> relu -> [512,32,20,20]
// grid (2, 512): x = oh-supertile (10 oh rows), y = batch. block 320.
// LDS: x tile 4ch x 44 rows x 84 = 59.1 KB. Weights from global (L1).
// thread: ocg(8) x [tile(2) x ow(20)] -> 4 oc x 5 oh x 1 ow = 20 outputs.
__global__ __launch_bounds__(320) void conv1_k(const float* __restrict__ x,
                                               const float* __restrict__ w,
                                               const float* __restrict__ bias,
                                               float* __restrict__ y) {
    __shared__ float xt[4 * 44 * 84];  // 14784 floats
    const int tid = threadIdx.x;
    const int sup = blockIdx.x;        // 0..1
    const int b   = blockIdx.y;

    // stage: rows ih = sup*40 .. sup*40+43, all 4 ch, 84 wide (21 float4 per row)
    {
        const float* xb = x + (size_t)b * 28224;  // 4*84*84
        for (int i = tid; i < 3696; i += 320) {   // 4*44*21 float4s
            const int row = i / 21, col = i % 21;
            const int ic = row / 44, r = row % 44;
            const float4 v = *(const float4*)(xb + ic * 7056 + (sup * 40 + r) * 84 + col * 4);
            *(float4*)(xt + (ic * 44 + r) * 84 + col * 4) = v;
        }
    }
    __syncthreads();

    const int ocg  = tid / 40;        // 0..7
    const int r    = tid % 40;
    const int tile = r / 20;          // 0..1
    const int ow   = r % 20;

    float acc[4][5];
    #pragma unroll
    for (int i = 0; i < 4; ++i)
        #pragma unroll
        for (int j = 0; j < 5; ++j) acc[i][j] = bias[ocg * 4 + i];

    #pragma unroll
    for (int ic = 0; ic < 4; ++ic) {
        #pragma unroll
        for (int kh = 0; kh < 8; ++kh) {
            float4 wv[4][2];
            #pragma unroll
            for (int i = 0; i < 4; ++i) {
                const float* wp = w + ((ocg * 4 + i) * 4 + ic) * 64 + kh * 8;
                wv[i][0] = *(const float4*)(wp);
                wv[i][1] = *(const float4*)(wp + 4);
            }
            #pragma unroll
            for (int j = 0; j < 5; ++j) {
                const int ihl = tile * 20 + j * 4 + kh;  // 0..43
                const float4 x0 = *(const float4*)(xt + (ic * 44 + ihl) * 84 + ow * 4);
                const float4 x1 = *(const float4*)(xt + (ic * 44 + ihl) * 84 + ow * 4 + 4);
                #pragma unroll
                for (int i = 0; i < 4; ++i) {
                    acc[i][j] += x0.x * wv[i][0].x + x0.y * wv[i][0].y
                               + x0.z * wv[i][0].z + x0.w * wv[i][0].w
                               + x1.x * wv[i][1].x + x1.y * wv[i][1].y
                               + x1.z * wv[i][1].z + x1.w * wv[i][1].w;
                }
            }
        }
    }

    #pragma unroll
    for (int i = 0; i < 4; ++i) {
        const int oc = ocg * 4 + i;
        #pragma unroll
        for (int j = 0; j < 5; ++j) {
            const int oh = sup * 10 + tile * 5 + j;
            y[(((size_t)b * 32 + oc) * 20 + oh) * 20 + ow] = fmaxf(acc[i][j], 0.f);
        }
    }
}

// ---------------- conv2 tiled: [512,32,20,20] * [64,32,4,4] s2 -> relu -> [512,64,9,9]
// grid 512 (one batch per block). block 192. LDS: full input 32x20x20 = 51.2 KB.
// thread (t<144): ocg(16) x oh(9) -> 4 oc x 9 ow = 36 outputs.
__global__ __launch_bounds__(192) void conv2_k(const float* __restrict__ x,
                                               const float* __restrict__ w,
                                               const float* __restrict__ bias,
                                               float* __restrict__ y) {
    __shared__ float xt[12800];
    const int tid = threadIdx.x;
    const int b = blockIdx.x;

    for (int i = tid; i < 3200; i += 192)
        *(float4*)(xt + i * 4) = *(const float4*)(x + (size_t)b * 12800 + i * 4);
    __syncthreads();

    if (tid < 144) {
        const int ocg = tid / 9;   // 0..15
        const int oh  = tid % 9;

        float acc[4][9];
        #pragma unroll
        for (int i = 0; i < 4; ++i)
            #pragma unroll
            for (int ow = 0; ow < 9; ++ow) acc[i][ow] = bias[ocg * 4 + i];

        for (int ic = 0; ic < 32; ++ic) {
            #pragma unroll
            for (int kh = 0; kh < 4; ++kh) {
                const int ih = oh * 2 + kh;  // 0..19
                const float* xr = xt + ic * 400 + ih * 20;
                float xv[20];
                #pragma unroll
                for (int q = 0; q < 5; ++q) {
                    const float4 v = *(const float4*)(xr + q * 4);
                    xv[q * 4 + 0] = v.x; xv[q * 4 + 1] = v.y;
                    xv[q * 4 + 2] = v.z; xv[q * 4 + 3] = v.w;
                }
                float4 wq[4];
                #pragma unroll
                for (int i = 0; i < 4; ++i)
                    wq[i] = *(const float4*)(w + (((ocg * 4 + i) * 32 + ic) * 16) + kh * 4);
                #pragma unroll
                for (int i = 0; i < 4; ++i) {
                    #pragma unroll
                    for (int ow = 0; ow < 9; ++ow) {
                        acc[i][ow] += xv[ow * 2 + 0] * wq[i].x + xv[ow * 2 + 1] * wq[i].y
                                    + xv[ow * 2 + 2] * wq[i].z + xv[ow * 2 + 3] * wq[i].w;
                    }
                }
            }
        }

        #pragma unroll
        for (int i = 0; i < 4; ++i) {
            const int oc = ocg * 4 + i;
            #pragma unroll
            for (int ow = 0; ow < 9; ++ow)
                y[(((size_t)b * 64 + oc) * 9 + oh) * 9 + ow] = fmaxf(acc[i][ow], 0.f);
        }
    }
}

// ---------------- repack c3w [64][64][3][3] -> [oc*64+ic][12] padded for float4 loads
__global__ __launch_bounds__(256) void repack_w3_k(const float* __restrict__ w,
                                                   float* __restrict__ wp) {
    const int i = blockIdx.x * 256 + threadIdx.x;  // 36864
    if (i < 36864) wp[(i / 9) * 12 + (i % 9)] = w[i];
}

// ---------------- conv3 tiled: [512,64,9,9] * [64,64,3,3] s1 -> relu -> [512,64,7,7]
// grid 256 (2 batches per block). block 256. LDS: 2 x 64ch x 9rows x 12(pad) = 55.3 KB.
// thread (t<224): bl(2) x ocg(16) x oh(7) -> 4 oc x 7 ow = 28 outputs.
__global__ __launch_bounds__(256) void conv3_k(const float* __restrict__ x,
                                               const float* __restrict__ wp,
                                               const float* __restrict__ bias,
                                               float* __restrict__ y) {
    __shared__ float xt[2 * 64 * 9 * 12];  // 13824
    const int tid = threadIdx.x;
    const int b0 = blockIdx.x * 2;

    for (int i = tid; i < 10368; i += 256) {  // 2 * 5184
        const int bl = i / 5184, j = i % 5184;
        const int ic = j / 81, rr = j % 81;
        xt[((bl * 64 + ic) * 9 + rr / 9) * 12 + rr % 9] = x[(size_t)(b0 + bl) * 5184 + j];
    }
    __syncthreads();

    if (tid < 224) {
        const int bl  = tid / 112;
        const int rem = tid % 112;
        const int ocg = rem / 7;   // 0..15
        const int oh  = rem % 7;

        float acc[4][7];
        #pragma unroll
        for (int i = 0; i < 4; ++i)
            #pragma unroll
            for (int ow = 0; ow < 7; ++ow) acc[i][ow] = bias[ocg * 4 + i];

        for (int ic = 0; ic < 64; ++ic) {
            float xr[3][12];
            #pragma unroll
            for (int r2 = 0; r2 < 3; ++r2) {
                const float* rp = xt + ((bl * 64 + ic) * 9 + oh + r2) * 12;
                *(float4*)(xr[r2] + 0) = *(const float4*)(rp + 0);
                *(float4*)(xr[r2] + 4) = *(const float4*)(rp + 4);
                *(float4*)(xr[r2] + 8) = *(const float4*)(rp + 8);
            }
            #pragma unroll
            for (int i = 0; i < 4; ++i) {
                const float* wr = wp + ((ocg * 4 + i) * 64 + ic) * 12;
                const float4 w0 = *(const float4*)(wr);
                const float4 w1 = *(const float4*)(wr + 4);
                const float4 w2 = *(const float4*)(wr + 8);
                const float wv[9] = {w0.x, w0.y, w0.z, w0.w, w1.x, w1.y, w1.z, w1.w, w2.x};
                #pragma unroll
                for (int kh = 0; kh < 3; ++kh)
                    #pragma unroll
                    for (int ow = 0; ow < 7; ++ow)
                        acc[i][ow] += xr[kh][ow + 0] * wv[kh * 3 + 0]
                                    + xr[kh][ow + 1] * wv[kh * 3 + 1]
                                    + xr[kh][ow + 2] * wv[kh * 3 + 2];
            }
        }

        #pragma unroll
        for (int i = 0; i < 4; ++i) {
            const int oc = ocg * 4 + i;
            #pragma unroll
            for (int ow = 0; ow < 7; ++ow)
                y[(((size_t)(b0 + bl) * 64 + oc) * 7 + oh) * 7 + ow] = fmaxf(acc[i][ow], 0.f);
        }
    }
}

// ---------------- fc split-K partial: [512,3136] @ [3136,256], 16 rows x 8 k-slices
// grid (8, 32): x = k-slice, y = row-group. block 256 (one col per thread).
__global__ __launch_bounds__(256) void fc_part_k(const float* __restrict__ a,
                                                 const float* __restrict__ w,
                                                 float* __restrict__ partial) {
    __shared__ float lin[16 * 392];  // 25.1 KB
    const int tid = threadIdx.x;
    const int ks = blockIdx.x;       // 0..7
    const int b0 = blockIdx.y * 16;

    for (int i = tid; i < 16 * 392; i += 256) {
        const int r = i / 392, kk = i % 392;
        lin[i] = a[(size_t)(b0 + r) * 3136 + ks * 392 + kk];
    }
    __syncthreads();

    float acc[16];
    #pragma unroll
    for (int r = 0; r < 16; ++r) acc[r] = 0.f;

    for (int kk = 0; kk < 392; kk += 2) {
        const float w0 = w[(size_t)(ks * 392 + kk) * 256 + tid];
        const float w1 = w[(size_t)(ks * 392 + kk + 1) * 256 + tid];
        #pragma unroll
        for (int r = 0; r < 16; ++r) {
            const float2 lv = *(const float2*)(lin + r * 392 + kk);
            acc[r] += lv.x * w0 + lv.y * w1;
        }
    }
    #pragma unroll
    for (int r = 0; r < 16; ++r)
        partial[(size_t)ks * 131072 + (b0 + r) * 256 + tid] = acc[r];
}

// ---------------- fc reduce: sum 8 partials + bias + relu -> feat [512,256]
__global__ __launch_bounds__(256) void fc_reduce_k(const float* __restrict__ partial,
                                                   const float* __restrict__ bias,
                                                   float* __restrict__ feat) {
    const int i = blockIdx.x * 256 + threadIdx.x;  // 131072
    float s = bias[i & 255];
    #pragma unroll
    for (int ks = 0; ks < 8; ++ks) s += partial[(size_t)ks * 131072 + i];
    feat[i] = fmaxf(s, 0.f);
}

// ---------------- dense 256->256 (+relu): block per row
__global__ __launch_bounds__(256) void dense256_relu_k(const float* __restrict__ in,
                                                       const float* __restrict__ w,
                                                       const float* __restrict__ bias,
                                                       float* __restrict__ out) {
    __shared__ float lin[256];
    const int b = blockIdx.x, tid = threadIdx.x;
    lin[tid] = in[b * 256 + tid];
    __syncthreads();
    float acc = bias[tid];
    #pragma unroll 8
    for (int k = 0; k < 256; ++k) acc += lin[k] * w[k * 256 + tid];
    out[b * 256 + tid] = fmaxf(acc, 0.f);
}

// ---------------- dense 256->64 (no relu): 4 rows/block
__global__ __launch_bounds__(256) void dense64_k(const float* __restrict__ in,
                                                 const float* __restrict__ w,
                                                 const float* __restrict__ bias,
                                                 float* __restrict__ out) {
    __shared__ float lin[4 * 256];
    const int tid = threadIdx.x;
    const int b0 = blockIdx.x * 4;
    for (int i = tid; i < 1024; i += 256) lin[i] = in[b0 * 256 + i];
    __syncthreads();
    const int r = tid >> 6, n = tid & 63;
    float acc = bias[n];
    #pragma unroll 8
    for (int k = 0; k < 256; ++k) acc += lin[r * 256 + k] * w[k * 64 + n];
    out[(b0 + r) * 64 + n] = acc;
}

// ---------------- dense 256->1 (no relu): one wave per row
__global__ __launch_bounds__(64) void dense1_k(const float* __restrict__ in,
                                               const float* __restrict__ w,
                                               const float* __restrict__ bias,
                                               float* __restrict__ out) {
    const int b = blockIdx.x, l = threadIdx.x;
    const float4 hv = *(const float4*)(in + b * 256 + l * 4);
    const float4 wv = *(const float4*)(w + l * 4);
    float p = hv.x * wv.x + hv.y * wv.y + hv.z * wv.z + hv.w * wv.w;
    #pragma unroll
    for (int off = 32; off > 0; off >>= 1) p += __shfl_down(p, off);
    if (l == 0) out[b] = p + bias[0];
}

// ---------------- transpose phi_y [512,64] -> [64,512]
__global__ __launch_bounds__(256) void transpose_phi_k(const float* __restrict__ phi,
                                                       float* __restrict__ phiT) {
    const int idx = blockIdx.x * 256 + threadIdx.x;  // 32768
    const int j = idx >> 6, k = idx & 63;
    phiT[k * 512 + j] = phi[idx];
}

// ---------------- per-row logits + logsumexp + diag
__global__ __launch_bounds__(256) void row_lse_k(const float* __restrict__ phi_x,
                                                 const float* __restrict__ phiYT,
                                                 const float* __restrict__ c_y,
                                                 float* __restrict__ row_lse,
                                                 float* __restrict__ row_diag) {
    const int i = blockIdx.x, tid = threadIdx.x;
    __shared__ float px[64];
    __shared__ float red[256];
    if (tid < 64) px[tid] = phi_x[i * 64 + tid];
    __syncthreads();

    float lg[2];
    #pragma unroll
    for (int q = 0; q < 2; ++q) {
        const int j = tid + q * 256;
        float m = -1e30f;
        #pragma unroll 8
        for (int k = 0; k < 32; ++k) m = fmaxf(m, px[k] - phiYT[k * 512 + j]);
        const float maxc = fmaxf(m, 0.f);
        float s = 0.f;
        #pragma unroll 8
        for (int k = 32; k < 64; ++k) {
            const float d = px[k] - phiYT[k * 512 + j];
            s += d * d;
        }
        lg[q] = c_y[j] - (maxc + sqrtf(s + 1e-8f));
    }
    if ((i & 255) == tid) row_diag[i] = lg[i >> 8];

    red[tid] = fmaxf(lg[0], lg[1]);
    __syncthreads();
    for (int s = 128; s > 0; s >>= 1) {
        if (tid < s) red[tid] = fmaxf(red[tid], red[tid + s]);
        __syncthreads();
    }
    const float m = red[0];
    __syncthreads();
    red[tid] = expf(lg[0] - m) + expf(lg[1] - m);
    __syncthreads();
    for (int s = 128; s > 0; s >>= 1) {
        if (tid < s) red[tid] += red[tid + s];
        __syncthreads();
    }
    if (tid == 0) row_lse[i] = m + logf(red[0]);
}

// ---------------- final scalar loss
__global__ __launch_bounds__(512) void loss_k(const float* __restrict__ row_lse,
                                              const float* __restrict__ row_diag,
                                              float* __restrict__ out) {
    __shared__ float r1[512], r2[512];
    const int t = threadIdx.x;
    const float lse = row_lse[t], dg = row_diag[t];
    r1[t] = lse - dg;
    const float l = lse + 1e-6f;
    r2[t] = l * l;
    __syncthreads();
    for (int s = 256; s > 0; s >>= 1) {
        if (t < s) { r1[t] += r1[t + s]; r2[t] += r2[t + s]; }
        __syncthreads();
    }
    if (t == 0) out[0] = r1[0] / 512.f + 0.1f * (r2[0] / 512.f);
}

extern "C" void kernel_launch(void* const* d_in, const int* in_sizes, int n_in,
                              void* d_out, int out_size, void* d_ws, size_t ws_size,
                              hipStream_t stream) {
    const float* curr = (const float*)d_in[0];
    const float* nxt  = (const float*)d_in[1];
    const float* c1w  = (const float*)d_in[2];
    const float* c1b  = (const float*)d_in[3];
    const float* c2w  = (const float*)d_in[4];
    const float* c2b  = (const float*)d_in[5];
    const float* c3w  = (const float*)d_in[6];
    const float* c3b  = (const float*)d_in[7];
    const float* fcw  = (const float*)d_in[8];
    const float* fcb  = (const float*)d_in[9];
    const float* e1w  = (const float*)d_in[10];
    const float* e1b  = (const float*)d_in[11];
    const float* e2w  = (const float*)d_in[12];
    const float* e2b  = (const float*)d_in[13];
    const float* pw1  = (const float*)d_in[14];
    const float* pb1  = (const float*)d_in[15];
    const float* pw2  = (const float*)d_in[16];
    const float* pb2  = (const float*)d_in[17];

    float* ws = (float*)d_ws;
    float* a1      = ws;                   // 6,553,600
    float* a2      = a1 + 6553600;         // 2,654,208
    float* a3      = a2 + 2654208;         // 1,605,632
    float* wp3     = a3 + 1605632;         // 49,152
    float* fcpart  = wp3 + 49152;          // 1,048,576
    float* feat_c  = fcpart + 1048576;     // 131,072
    float* feat_n  = feat_c + 131072;      // 131,072
    float* h1      = feat_n + 131072;      // 131,072
    float* phi_x   = h1 + 131072;          // 32,768
    float* phi_y   = phi_x + 32768;        // 32,768
    float* phiYT   = phi_y + 32768;        // 32,768
    float* c_y     = phiYT + 32768;        // 512
    float* rlse    = c_y + 512;            // 512
    float* rdiag   = rlse + 512;           // 512

    repack_w3_k<<<144, 256, 0, stream>>>(c3w, wp3);

    for (int pass = 0; pass < 2; ++pass) {
        const float* obs = pass ? nxt : curr;
        float* feat = pass ? feat_n : feat_c;
        conv1_k<<<dim3(2, 512), 320, 0, stream>>>(obs, c1w, c1b, a1);
        conv2_k<<<512, 192, 0, stream>>>(a1, c2w, c2b, a2);
        conv3_k<<<256, 256, 0, stream>>>(a2, wp3, c3b, a3);
        fc_part_k<<<dim3(8, 32), 256, 0, stream>>>(a3, fcw, fcpart);
        fc_reduce_k<<<512, 256, 0, stream>>>(fcpart, fcb, feat);
    }

    dense256_relu_k<<<512, 256, 0, stream>>>(feat_c, e1w, e1b, h1);
    dense64_k<<<128, 256, 0, stream>>>(h1, e2w, e2b, phi_x);
    dense256_relu_k<<<512, 256, 0, stream>>>(feat_n, e1w, e1b, h1);
    dense64_k<<<128, 256, 0, stream>>>(h1, e2w, e2b, phi_y);
    dense256_relu_k<<<512, 256, 0, stream>>>(feat_n, pw1, pb1, h1);
    dense1_k<<<512, 64, 0, stream>>>(h1, pw2, pb2, c_y);

    transpose_phi_k<<<128, 256, 0, stream>>>(phi_y, phiYT);
    row_lse_k<<<512, 256, 0, stream>>>(phi_x, phiYT, c_y, rlse, rdiag);
    loss_k<<<1, 512, 0, stream>>>(rlse, rdiag, (float*)d_out);
}

// Round 3
// 655.528 us; speedup vs baseline: 3.3454x; 1.3109x over previous
//
#include <hip/hip_runtime.h>
#include <math.h>

typedef __attribute__((ext_vector_type(8))) short bf16x8;
typedef __attribute__((ext_vector_type(4))) float f32x4;

static __device__ __forceinline__ ushort f2bf(float x) {
    union { float f; unsigned u; } a; a.f = x;
    unsigned r = a.u + 0x7fff + ((a.u >> 16) & 1);   // RNE
    return (ushort)(r >> 16);
}

// ---------------- conv1 tiled: [512,4,84,84] * [32,4,8,8] s4 -> relu -> [512,32,20,20]
__global__ __launch_bounds__(320) void conv1_k(const float* __restrict__ x,
                                               const float* __restrict__ w,
                                               const float* __restrict__ bias,
                                               float* __restrict__ y) {
    __shared__ float xt[4 * 44 * 84];
    const int tid = threadIdx.x;
    const int sup = blockIdx.x;
    const int b   = blockIdx.y;

    {
        const float* xb = x + (size_t)b * 28224;
        for (int i = tid; i < 3696; i += 320) {
            const int row = i / 21, col = i % 21;
            const int ic = row / 44, r = row % 44;
            const float4 v = *(const float4*)(xb + ic * 7056 + (sup * 40 + r) * 84 + col * 4);
            *(float4*)(xt + (ic * 44 + r) * 84 + col * 4) = v;
        }
    }
    __syncthreads();

    const int ocg  = tid / 40;
    const int r    = tid % 40;
    const int tile = r / 20;
    const int ow   = r % 20;

    float acc[4][5];
    #pragma unroll
    for (int i = 0; i < 4; ++i)
        #pragma unroll
        for (int j = 0; j < 5; ++j) acc[i][j] = bias[ocg * 4 + i];

    #pragma unroll
    for (int ic = 0; ic < 4; ++ic) {
        #pragma unroll
        for (int kh = 0; kh < 8; ++kh) {
            float4 wv[4][2];
            #pragma unroll
            for (int i = 0; i < 4; ++i) {
                const float* wp = w + ((ocg * 4 + i) * 4 + ic) * 64 + kh * 8;
                wv[i][0] = *(const float4*)(wp);
                wv[i][1] = *(const float4*)(wp + 4);
            }
            #pragma unroll
            for (int j = 0; j < 5; ++j) {
                const int ihl = tile * 20 + j * 4 + kh;
                const float4 x0 = *(const float4*)(xt + (ic * 44 + ihl) * 84 + ow * 4);
                const float4 x1 = *(const float4*)(xt + (ic * 44 + ihl) * 84 + ow * 4 + 4);
                #pragma unroll
                for (int i = 0; i < 4; ++i) {
                    acc[i][j] += x0.x * wv[i][0].x + x0.y * wv[i][0].y
                               + x0.z * wv[i][0].z + x0.w * wv[i][0].w
                               + x1.x * wv[i][1].x + x1.y * wv[i][1].y
                               + x1.z * wv[i][1].z + x1.w * wv[i][1].w;
                }
            }
        }
    }

    #pragma unroll
    for (int i = 0; i < 4; ++i) {
        const int oc = ocg * 4 + i;
        #pragma unroll
        for (int j = 0; j < 5; ++j) {
            const int oh = sup * 10 + tile * 5 + j;
            y[(((size_t)b * 32 + oc) * 20 + oh) * 20 + ow] = fmaxf(acc[i][j], 0.f);
        }
    }
}

// ---------------- repack c2w [64][32][4][4] fp32 -> bf16 MFMA A-fragment order
// wp[((wv*16 + kk)*64 + l)*8 + j] = bf16(w[oc=wv*16+(l&15)][k=kk*32+(l>>4)*8+j])
__global__ __launch_bounds__(256) void repack_w2_k(const float* __restrict__ w,
                                                   ushort* __restrict__ wp) {
    const int t = blockIdx.x * 256 + threadIdx.x;  // 32768
    const int j = t & 7, l = (t >> 3) & 63, kk = (t >> 9) & 15, wv = t >> 13;
    const int oc = wv * 16 + (l & 15);
    const int k  = kk * 32 + ((l >> 4) * 8) + j;
    wp[t] = f2bf(w[oc * 512 + k]);
}

// ---------------- conv2 MFMA: [512,32,20,20] * [64,32,4,4] s2 -> relu -> [512,64,9,9]
// one image per block, 256 threads (4 waves). GEMM: D[oc=64][pos=81pad96], K=512.
// wave = one 16-oc tile; 6 pos-tiles of 16; A=weights (repacked frag order),
// B=patches gathered from LDS (bf16). acc = 6 x f32x4.
__global__ __launch_bounds__(256) void conv2_mfma_k(const float* __restrict__ x,
                                                    const ushort* __restrict__ wpack,
                                                    const float* __restrict__ bias,
                                                    float* __restrict__ y) {
    __shared__ ushort xt[12800];  // 32ch x 20 x 20 bf16 = 25.6 KB
    const int tid = threadIdx.x;
    const int b = blockIdx.x;

    const float4* xb = (const float4*)(x + (size_t)b * 12800);
    for (int i = tid; i < 3200; i += 256) {
        const float4 v = xb[i];
        ushort4 u;
        u.x = f2bf(v.x); u.y = f2bf(v.y); u.z = f2bf(v.z); u.w = f2bf(v.w);
        *(ushort4*)(xt + i * 4) = u;
    }
    __syncthreads();

    const int wv   = tid >> 6;   // 0..3 = oc-tile
    const int l    = tid & 63;
    const int quad = l >> 4;
    const int col  = l & 15;     // pos offset within tile / A's m-lane

    int ohs[6], ows[6];
    #pragma unroll
    for (int t = 0; t < 6; ++t) {
        int pos = t * 16 + col; if (pos > 80) pos = 80;
        ohs[t] = pos / 9; ows[t] = pos % 9;
    }
    const int ic_off = quad >> 1;       // k -> ic sub-offset
    const int kh2    = (quad & 1) * 2;  // k -> kh base

    float bias_v[4];
    #pragma unroll
    for (int r2 = 0; r2 < 4; ++r2) bias_v[r2] = bias[wv * 16 + quad * 4 + r2];

    f32x4 acc[6];
    #pragma unroll
    for (int t = 0; t < 6; ++t) acc[t] = (f32x4){0.f, 0.f, 0.f, 0.f};

    const bf16x8* wp = (const bf16x8*)wpack;

    for (int kk = 0; kk < 16; ++kk) {
        const bf16x8 a = wp[(wv * 16 + kk) * 64 + l];
        const int ic = kk * 2 + ic_off;
        #pragma unroll
        for (int t = 0; t < 6; ++t) {
            const int base = ic * 400 + (ohs[t] * 2 + kh2) * 20 + ows[t] * 2;
            const unsigned* p0 = (const unsigned*)(xt + base);        // 4B aligned (base even)
            const unsigned* p1 = (const unsigned*)(xt + base + 20);
            union { unsigned u[4]; bf16x8 v; } f;
            f.u[0] = p0[0]; f.u[1] = p0[1];   // row kh2:   kw 0..3
            f.u[2] = p1[0]; f.u[3] = p1[1];   // row kh2+1: kw 0..3
            acc[t] = __builtin_amdgcn_mfma_f32_16x16x32_bf16(a, f.v, acc[t], 0, 0, 0);
        }
    }

    #pragma unroll
    for (int t = 0; t < 6; ++t) {
        const int pos = t * 16 + col;
        if (pos < 81) {
            #pragma unroll
            for (int r2 = 0; r2 < 4; ++r2) {
                const int oc = wv * 16 + quad * 4 + r2;
                y[((size_t)b * 64 + oc) * 81 + pos] = fmaxf(acc[t][r2] + bias_v[r2], 0.f);
            }
        }
    }
}

// ---------------- repack c3w [64][64][3][3] -> [oc*64+ic][12] padded
__global__ __launch_bounds__(256) void repack_w3_k(const float* __restrict__ w,
                                                   float* __restrict__ wp) {
    const int i = blockIdx.x * 256 + threadIdx.x;
    if (i < 36864) wp[(i / 9) * 12 + (i % 9)] = w[i];
}

// ---------------- conv3 tiled: [512,64,9,9] * [64,64,3,3] s1 -> relu -> [512,64,7,7]
__global__ __launch_bounds__(256) void conv3_k(const float* __restrict__ x,
                                               const float* __restrict__ wp,
                                               const float* __restrict__ bias,
                                               float* __restrict__ y) {
    __shared__ float xt[2 * 64 * 9 * 12];
    const int tid = threadIdx.x;
    const int b0 = blockIdx.x * 2;

    for (int i = tid; i < 10368; i += 256) {
        const int bl = i / 5184, j = i % 5184;
        const int ic = j / 81, rr = j % 81;
        xt[((bl * 64 + ic) * 9 + rr / 9) * 12 + rr % 9] = x[(size_t)(b0 + bl) * 5184 + j];
    }
    __syncthreads();

    if (tid < 224) {
        const int bl  = tid / 112;
        const int rem = tid % 112;
        const int ocg = rem / 7;
        const int oh  = rem % 7;

        float acc[4][7];
        #pragma unroll
        for (int i = 0; i < 4; ++i)
            #pragma unroll
            for (int ow = 0; ow < 7; ++ow) acc[i][ow] = bias[ocg * 4 + i];

        for (int ic = 0; ic < 64; ++ic) {
            float xr[3][12];
            #pragma unroll
            for (int r2 = 0; r2 < 3; ++r2) {
                const float* rp = xt + ((bl * 64 + ic) * 9 + oh + r2) * 12;
                *(float4*)(xr[r2] + 0) = *(const float4*)(rp + 0);
                *(float4*)(xr[r2] + 4) = *(const float4*)(rp + 4);
                *(float4*)(xr[r2] + 8) = *(const float4*)(rp + 8);
            }
            #pragma unroll
            for (int i = 0; i < 4; ++i) {
                const float* wr = wp + ((ocg * 4 + i) * 64 + ic) * 12;
                const float4 w0 = *(const float4*)(wr);
                const float4 w1 = *(const float4*)(wr + 4);
                const float4 w2 = *(const float4*)(wr + 8);
                const float wv[9] = {w0.x, w0.y, w0.z, w0.w, w1.x, w1.y, w1.z, w1.w, w2.x};
                #pragma unroll
                for (int kh = 0; kh < 3; ++kh)
                    #pragma unroll
                    for (int ow = 0; ow < 7; ++ow)
                        acc[i][ow] += xr[kh][ow + 0] * wv[kh * 3 + 0]
                                    + xr[kh][ow + 1] * wv[kh * 3 + 1]
                                    + xr[kh][ow + 2] * wv[kh * 3 + 2];
            }
        }

        #pragma unroll
        for (int i = 0; i < 4; ++i) {
            const int oc = ocg * 4 + i;
            #pragma unroll
            for (int ow = 0; ow < 7; ++ow)
                y[(((size_t)(b0 + bl) * 64 + oc) * 7 + oh) * 7 + ow] = fmaxf(acc[i][ow], 0.f);
        }
    }
}

// ---------------- fc split-K partial
__global__ __launch_bounds__(256) void fc_part_k(const float* __restrict__ a,
                                                 const float* __restrict__ w,
                                                 float* __restrict__ partial) {
    __shared__ float lin[16 * 392];
    const int tid = threadIdx.x;
    const int ks = blockIdx.x;
    const int b0 = blockIdx.y * 16;

    for (int i = tid; i < 16 * 392; i += 256) {
        const int r = i / 392, kk = i % 392;
        lin[i] = a[(size_t)(b0 + r) * 3136 + ks * 392 + kk];
    }
    __syncthreads();

    float acc[16];
    #pragma unroll
    for (int r = 0; r < 16; ++r) acc[r] = 0.f;

    for (int kk = 0; kk < 392; kk += 2) {
        const float w0 = w[(size_t)(ks * 392 + kk) * 256 + tid];
        const float w1 = w[(size_t)(ks * 392 + kk + 1) * 256 + tid];
        #pragma unroll
        for (int r = 0; r < 16; ++r) {
            const float2 lv = *(const float2*)(lin + r * 392 + kk);
            acc[r] += lv.x * w0 + lv.y * w1;
        }
    }
    #pragma unroll
    for (int r = 0; r < 16; ++r)
        partial[(size_t)ks * 131072 + (b0 + r) * 256 + tid] = acc[r];
}

// ---------------- fc reduce
__global__ __launch_bounds__(256) void fc_reduce_k(const float* __restrict__ partial,
                                                   const float* __restrict__ bias,
                                                   float* __restrict__ feat) {
    const int i = blockIdx.x * 256 + threadIdx.x;
    float s = bias[i & 255];
    #pragma unroll
    for (int ks = 0; ks < 8; ++ks) s += partial[(size_t)ks * 131072 + i];
    feat[i] = fmaxf(s, 0.f);
}

// ---------------- dense 256->256 (+relu)
__global__ __launch_bounds__(256) void dense256_relu_k(const float* __restrict__ in,
                                                       const float* __restrict__ w,
                                                       const float* __restrict__ bias,
                                                       float* __restrict__ out) {
    __shared__ float lin[256];
    const int b = blockIdx.x, tid = threadIdx.x;
    lin[tid] = in[b * 256 + tid];
    __syncthreads();
    float acc = bias[tid];
    #pragma unroll 8
    for (int k = 0; k < 256; ++k) acc += lin[k] * w[k * 256 + tid];
    out[b * 256 + tid] = fmaxf(acc, 0.f);
}

// ---------------- dense 256->64
__global__ __launch_bounds__(256) void dense64_k(const float* __restrict__ in,
                                                 const float* __restrict__ w,
                                                 const float* __restrict__ bias,
                                                 float* __restrict__ out) {
    __shared__ float lin[4 * 256];
    const int tid = threadIdx.x;
    const int b0 = blockIdx.x * 4;
    for (int i = tid; i < 1024; i += 256) lin[i] = in[b0 * 256 + i];
    __syncthreads();
    const int r = tid >> 6, n = tid & 63;
    float acc = bias[n];
    #pragma unroll 8
    for (int k = 0; k < 256; ++k) acc += lin[r * 256 + k] * w[k * 64 + n];
    out[(b0 + r) * 64 + n] = acc;
}

// ---------------- dense 256->1
__global__ __launch_bounds__(64) void dense1_k(const float* __restrict__ in,
                                               const float* __restrict__ w,
                                               const float* __restrict__ bias,
                                               float* __restrict__ out) {
    const int b = blockIdx.x, l = threadIdx.x;
    const float4 hv = *(const float4*)(in + b * 256 + l * 4);
    const float4 wv = *(const float4*)(w + l * 4);
    float p = hv.x * wv.x + hv.y * wv.y + hv.z * wv.z + hv.w * wv.w;
    #pragma unroll
    for (int off = 32; off > 0; off >>= 1) p += __shfl_down(p, off);
    if (l == 0) out[b] = p + bias[0];
}

// ---------------- transpose phi_y [512,64] -> [64,512]
__global__ __launch_bounds__(256) void transpose_phi_k(const float* __restrict__ phi,
                                                       float* __restrict__ phiT) {
    const int idx = blockIdx.x * 256 + threadIdx.x;
    const int j = idx >> 6, k = idx & 63;
    phiT[k * 512 + j] = phi[idx];
}

// ---------------- per-row logits + logsumexp + diag
__global__ __launch_bounds__(256) void row_lse_k(const float* __restrict__ phi_x,
                                                 const float* __restrict__ phiYT,
                                                 const float* __restrict__ c_y,
                                                 float* __restrict__ row_lse,
                                                 float* __restrict__ row_diag) {
    const int i = blockIdx.x, tid = threadIdx.x;
    __shared__ float px[64];
    __shared__ float red[256];
    if (tid < 64) px[tid] = phi_x[i * 64 + tid];
    __syncthreads();

    float lg[2];
    #pragma unroll
    for (int q = 0; q < 2; ++q) {
        const int j = tid + q * 256;
        float m = -1e30f;
        #pragma unroll 8
        for (int k = 0; k < 32; ++k) m = fmaxf(m, px[k] - phiYT[k * 512 + j]);
        const float maxc = fmaxf(m, 0.f);
        float s = 0.f;
        #pragma unroll 8
        for (int k = 32; k < 64; ++k) {
            const float d = px[k] - phiYT[k * 512 + j];
            s += d * d;
        }
        lg[q] = c_y[j] - (maxc + sqrtf(s + 1e-8f));
    }
    if ((i & 255) == tid) row_diag[i] = lg[i >> 8];

    red[tid] = fmaxf(lg[0], lg[1]);
    __syncthreads();
    for (int s = 128; s > 0; s >>= 1) {
        if (tid < s) red[tid] = fmaxf(red[tid], red[tid + s]);
        __syncthreads();
    }
    const float m = red[0];
    __syncthreads();
    red[tid] = expf(lg[0] - m) + expf(lg[1] - m);
    __syncthreads();
    for (int s = 128; s > 0; s >>= 1) {
        if (tid < s) red[tid] += red[tid + s];
        __syncthreads();
    }
    if (tid == 0) row_lse[i] = m + logf(red[0]);
}

// ---------------- final scalar loss
__global__ __launch_bounds__(512) void loss_k(const float* __restrict__ row_lse,
                                              const float* __restrict__ row_diag,
                                              float* __restrict__ out) {
    __shared__ float r1[512], r2[512];
    const int t = threadIdx.x;
    const float lse = row_lse[t], dg = row_diag[t];
    r1[t] = lse - dg;
    const float l = lse + 1e-6f;
    r2[t] = l * l;
    __syncthreads();
    for (int s = 256; s > 0; s >>= 1) {
        if (t < s) { r1[t] += r1[t + s]; r2[t] += r2[t + s]; }
        __syncthreads();
    }
    if (t == 0) out[0] = r1[0] / 512.f + 0.1f * (r2[0] / 512.f);
}

extern "C" void kernel_launch(void* const* d_in, const int* in_sizes, int n_in,
                              void* d_out, int out_size, void* d_ws, size_t ws_size,
                              hipStream_t stream) {
    const float* curr = (const float*)d_in[0];
    const float* nxt  = (const float*)d_in[1];
    const float* c1w  = (const float*)d_in[2];
    const float* c1b  = (const float*)d_in[3];
    const float* c2w  = (const float*)d_in[4];
    const float* c2b  = (const float*)d_in[5];
    const float* c3w  = (const float*)d_in[6];
    const float* c3b  = (const float*)d_in[7];
    const float* fcw  = (const float*)d_in[8];
    const float* fcb  = (const float*)d_in[9];
    const float* e1w  = (const float*)d_in[10];
    const float* e1b  = (const float*)d_in[11];
    const float* e2w  = (const float*)d_in[12];
    const float* e2b  = (const float*)d_in[13];
    const float* pw1  = (const float*)d_in[14];
    const float* pb1  = (const float*)d_in[15];
    const float* pw2  = (const float*)d_in[16];
    const float* pb2  = (const float*)d_in[17];

    float* ws = (float*)d_ws;
    float* a1      = ws;                   // 6,553,600
    float* a2      = a1 + 6553600;         // 2,654,208
    float* a3      = a2 + 2654208;         // 1,605,632
    float* wp3     = a3 + 1605632;         // 49,152
    float* wp2f    = wp3 + 49152;          // 16,384 floats = 32,768 bf16
    float* fcpart  = wp2f + 16384;         // 1,048,576
    float* feat_c  = fcpart + 1048576;     // 131,072
    float* feat_n  = feat_c + 131072;      // 131,072
    float* h1      = feat_n + 131072;      // 131,072
    float* phi_x   = h1 + 131072;          // 32,768
    float* phi_y   = phi_x + 32768;        // 32,768
    float* phiYT   = phi_y + 32768;        // 32,768
    float* c_y     = phiYT + 32768;        // 512
    float* rlse    = c_y + 512;            // 512
    float* rdiag   = rlse + 512;           // 512
    ushort* wp2    = (ushort*)wp2f;

    repack_w3_k<<<144, 256, 0, stream>>>(c3w, wp3);
    repack_w2_k<<<128, 256, 0, stream>>>(c2w, wp2);

    for (int pass = 0; pass < 2; ++pass) {
        const float* obs = pass ? nxt : curr;
        float* feat = pass ? feat_n : feat_c;
        conv1_k<<<dim3(2, 512), 320, 0, stream>>>(obs, c1w, c1b, a1);
        conv2_mfma_k<<<512, 256, 0, stream>>>(a1, wp2, c2b, a2);
        conv3_k<<<256, 256, 0, stream>>>(a2, wp3, c3b, a3);
        fc_part_k<<<dim3(8, 32), 256, 0, stream>>>(a3, fcw, fcpart);
        fc_reduce_k<<<512, 256, 0, stream>>>(fcpart, fcb, feat);
    }

    dense256_relu_k<<<512, 256, 0, stream>>>(feat_c, e1w, e1b, h1);
    dense64_k<<<128, 256, 0, stream>>>(h1, e2w, e2b, phi_x);
    dense256_relu_k<<<512, 256, 0, stream>>>(feat_n, e1w, e1b, h1);
    dense64_k<<<128, 256, 0, stream>>>(h1, e2w, e2b, phi_y);
    dense256_relu_k<<<512, 256, 0, stream>>>(feat_n, pw1, pb1, h1);
    dense1_k<<<512, 64, 0, stream>>>(h1, pw2, pb2, c_y);

    transpose_phi_k<<<128, 256, 0, stream>>>(phi_y, phiYT);
    row_lse_k<<<512, 256, 0, stream>>>(phi_x, phiYT, c_y, rlse, rdiag);
    loss_k<<<1, 512, 0, stream>>>(rlse, rdiag, (float*)d_out);
}

// Round 4
// 384.737 us; speedup vs baseline: 5.7001x; 1.7038x over previous
//
#include <hip/hip_runtime.h>
#include <math.h>

typedef __attribute__((ext_vector_type(8))) short bf16x8;
typedef __attribute__((ext_vector_type(4))) float f32x4;

static __device__ __forceinline__ ushort f2bf(float x) {
    union { float f; unsigned u; } a; a.f = x;
    unsigned r = a.u + 0x7fff + ((a.u >> 16) & 1);   // RNE
    return (ushort)(r >> 16);
}

// ============ weight repacks (bf16, MFMA A-fragment order) ============

// conv1 w [32][4][8][8] (= [oc][k], k=ic*64+kh*8+kw). wp1[((ot*8+kk)*64+l)*8+j]
__global__ __launch_bounds__(256) void repack_w1_k(const float* __restrict__ w,
                                                   ushort* __restrict__ wp) {
    const int t = blockIdx.x * 256 + threadIdx.x;  // 8192
    const int j = t & 7, l = (t >> 3) & 63, kk = (t >> 9) & 7, ot = t >> 12;
    const int oc = ot * 16 + (l & 15);
    const int k  = kk * 32 + ((l >> 4) * 8) + j;
    wp[t] = f2bf(w[oc * 256 + k]);
}

// conv2 w [64][32][4][4] -> wp2[((wv*16+kk)*64+l)*8+j], k=ic*16+kh*4+kw (K=512)
__global__ __launch_bounds__(256) void repack_w2_k(const float* __restrict__ w,
                                                   ushort* __restrict__ wp) {
    const int t = blockIdx.x * 256 + threadIdx.x;  // 32768
    const int j = t & 7, l = (t >> 3) & 63, kk = (t >> 9) & 15, wv = t >> 13;
    const int oc = wv * 16 + (l & 15);
    const int k  = kk * 32 + ((l >> 4) * 8) + j;
    wp[t] = f2bf(w[oc * 512 + k]);
}

// conv3 w [64][64][3][3] -> per (kp=kh*3+kw): A[oc][ic].
// wp3[(((kp*4+ot)*2+kk)*64+l)*8+j] = w[oc=ot*16+(l&15)][ic=kk*32+(l>>4)*8+j][kp]
__global__ __launch_bounds__(256) void repack_w3_k(const float* __restrict__ w,
                                                   ushort* __restrict__ wp) {
    const int t = blockIdx.x * 256 + threadIdx.x;  // 36864
    const int j = t & 7, l = (t >> 3) & 63, kk = (t >> 9) & 1;
    const int ot = (t >> 10) & 3, kp = t >> 12;
    const int oc = ot * 16 + (l & 15);
    const int ic = kk * 32 + ((l >> 4) * 8) + j;
    wp[t] = f2bf(w[(oc * 64 + ic) * 9 + kp]);
}

// fc w [3136][256] -> wfc[n*3136 + k'], k' = pos*64+oc (HWC-permuted K)
__global__ __launch_bounds__(256) void repack_wfc_k(const float* __restrict__ w,
                                                    ushort* __restrict__ wp) {
    const int t = blockIdx.x * 256 + threadIdx.x;  // 802816
    const int n = t / 3136, kp = t % 3136;
    const int pos = kp >> 6, oc = kp & 63;
    wp[t] = f2bf(w[(oc * 49 + pos) * 256 + n]);
}

// ============ conv1 MFMA: [512,4,84,84]fp32 * [32,4,8,8] s4 -> relu -> bf16 CHW [512,32,400]
__global__ __launch_bounds__(256) void conv1_mfma_k(const float* __restrict__ x,
                                                    const ushort* __restrict__ wpack,
                                                    const float* __restrict__ bias,
                                                    ushort* __restrict__ y) {
    __shared__ ushort xt[28224];  // 4ch x 84 x 84 bf16 = 56.4 KB
    const int tid = threadIdx.x, b = blockIdx.x;

    const float4* xb = (const float4*)(x + (size_t)b * 28224);
    for (int i = tid; i < 7056; i += 256) {
        const float4 v = xb[i];
        ushort4 u; u.x = f2bf(v.x); u.y = f2bf(v.y); u.z = f2bf(v.z); u.w = f2bf(v.w);
        *(ushort4*)(xt + i * 4) = u;
    }
    __syncthreads();

    const int wv = tid >> 6, l = tid & 63, q = l >> 4, col = l & 15;

    bf16x8 a[2][8];
    const bf16x8* wp = (const bf16x8*)wpack;
    #pragma unroll
    for (int ot = 0; ot < 2; ++ot)
        #pragma unroll
        for (int kk = 0; kk < 8; ++kk) a[ot][kk] = wp[(ot * 8 + kk) * 64 + l];

    float bv[2][4];
    #pragma unroll
    for (int ot = 0; ot < 2; ++ot)
        #pragma unroll
        for (int r = 0; r < 4; ++r) bv[ot][r] = bias[ot * 16 + q * 4 + r];

    for (int t = wv; t < 25; t += 4) {
        const int pos = t * 16 + col;      // < 400 always
        const int oh = pos / 20, ow = pos % 20;
        f32x4 acc0 = {0.f, 0.f, 0.f, 0.f}, acc1 = {0.f, 0.f, 0.f, 0.f};
        #pragma unroll
        for (int kk = 0; kk < 8; ++kk) {
            const int ickh = kk * 4 + q;
            const int ic = ickh >> 3, kh = ickh & 7;
            const int base = ic * 7056 + (oh * 4 + kh) * 84 + ow * 4;
            union { uint2 u2[2]; bf16x8 v; } f;
            f.u2[0] = *(const uint2*)(xt + base);
            f.u2[1] = *(const uint2*)(xt + base + 4);
            acc0 = __builtin_amdgcn_mfma_f32_16x16x32_bf16(a[0][kk], f.v, acc0, 0, 0, 0);
            acc1 = __builtin_amdgcn_mfma_f32_16x16x32_bf16(a[1][kk], f.v, acc1, 0, 0, 0);
        }
        #pragma unroll
        for (int r = 0; r < 4; ++r) {
            y[((size_t)b * 32 + q * 4 + r) * 400 + pos]      = f2bf(fmaxf(acc0[r] + bv[0][r], 0.f));
            y[((size_t)b * 32 + 16 + q * 4 + r) * 400 + pos] = f2bf(fmaxf(acc1[r] + bv[1][r], 0.f));
        }
    }
}

// ============ conv2 MFMA: bf16 CHW [512,32,20,20] * [64,32,4,4] s2 -> relu -> bf16 HWC [512,81,64]
__global__ __launch_bounds__(256) void conv2_mfma_k(const ushort* __restrict__ x,
                                                    const ushort* __restrict__ wpack,
                                                    const float* __restrict__ bias,
                                                    ushort* __restrict__ y) {
    __shared__ ushort xt[12800];  // 32ch x 20 x 20 bf16
    const int tid = threadIdx.x, b = blockIdx.x;

    const uint4* xg = (const uint4*)(x + (size_t)b * 12800);
    for (int i = tid; i < 1600; i += 256) *(uint4*)(xt + i * 8) = xg[i];
    __syncthreads();

    const int wv = tid >> 6, l = tid & 63, quad = l >> 4, col = l & 15;

    int ohs[6], ows[6];
    #pragma unroll
    for (int t = 0; t < 6; ++t) {
        int pos = t * 16 + col; if (pos > 80) pos = 80;
        ohs[t] = pos / 9; ows[t] = pos % 9;
    }
    const int ic_off = quad >> 1;
    const int kh2    = (quad & 1) * 2;

    float bias_v[4];
    #pragma unroll
    for (int r2 = 0; r2 < 4; ++r2) bias_v[r2] = bias[wv * 16 + quad * 4 + r2];

    f32x4 acc[6];
    #pragma unroll
    for (int t = 0; t < 6; ++t) acc[t] = (f32x4){0.f, 0.f, 0.f, 0.f};

    const bf16x8* wp = (const bf16x8*)wpack;

    for (int kk = 0; kk < 16; ++kk) {
        const bf16x8 a = wp[(wv * 16 + kk) * 64 + l];
        const int ic = kk * 2 + ic_off;
        #pragma unroll
        for (int t = 0; t < 6; ++t) {
            const int base = ic * 400 + (ohs[t] * 2 + kh2) * 20 + ows[t] * 2;
            const unsigned* p0 = (const unsigned*)(xt + base);
            const unsigned* p1 = (const unsigned*)(xt + base + 20);
            union { unsigned u[4]; bf16x8 v; } f;
            f.u[0] = p0[0]; f.u[1] = p0[1];
            f.u[2] = p1[0]; f.u[3] = p1[1];
            acc[t] = __builtin_amdgcn_mfma_f32_16x16x32_bf16(a, f.v, acc[t], 0, 0, 0);
        }
    }

    #pragma unroll
    for (int t = 0; t < 6; ++t) {
        const int pos = t * 16 + col;
        if (pos < 81) {
            ushort4 u;
            u.x = f2bf(fmaxf(acc[t][0] + bias_v[0], 0.f));
            u.y = f2bf(fmaxf(acc[t][1] + bias_v[1], 0.f));
            u.z = f2bf(fmaxf(acc[t][2] + bias_v[2], 0.f));
            u.w = f2bf(fmaxf(acc[t][3] + bias_v[3], 0.f));
            *(ushort4*)(y + (size_t)b * 5184 + pos * 64 + wv * 16 + quad * 4) = u;
        }
    }
}

// ============ conv3 MFMA: bf16 HWC [512,81,64] * [64,64,3,3] s1 -> relu -> bf16 HWC [512,49,64]
// 9 shifted 1x1 GEMMs; LDS pitch 68 to break bank aliasing.
__global__ __launch_bounds__(256) void conv3_mfma_k(const ushort* __restrict__ x,
                                                    const ushort* __restrict__ wpack,
                                                    const float* __restrict__ bias,
                                                    ushort* __restrict__ y) {
    __shared__ ushort xt[81 * 68];  // 11 KB
    const int tid = threadIdx.x, b = blockIdx.x;

    for (int i = tid; i < 1296; i += 256) {  // ushort4 chunks
        const int pos = i >> 4, ic4 = (i & 15) * 4;
        *(ushort4*)(xt + pos * 68 + ic4) = *(const ushort4*)(x + (size_t)b * 5184 + i * 4);
    }
    __syncthreads();

    const int ot = tid >> 6, l = tid & 63, q = l >> 4, col = l & 15;

    int ohs[4], ows[4];
    #pragma unroll
    for (int pt = 0; pt < 4; ++pt) {
        int pos = pt * 16 + col; if (pos > 48) pos = 48;
        ohs[pt] = pos / 7; ows[pt] = pos % 7;
    }

    float bv[4];
    #pragma unroll
    for (int r = 0; r < 4; ++r) bv[r] = bias[ot * 16 + q * 4 + r];

    f32x4 acc[4];
    #pragma unroll
    for (int pt = 0; pt < 4; ++pt) acc[pt] = (f32x4){0.f, 0.f, 0.f, 0.f};

    const bf16x8* wp = (const bf16x8*)wpack;

    #pragma unroll
    for (int kp = 0; kp < 9; ++kp) {
        const int kh = kp / 3, kw = kp % 3;
        #pragma unroll
        for (int kk = 0; kk < 2; ++kk) {
            const bf16x8 a = wp[((kp * 4 + ot) * 2 + kk) * 64 + l];
            #pragma unroll
            for (int pt = 0; pt < 4; ++pt) {
                const int rpos = (ohs[pt] + kh) * 9 + (ows[pt] + kw);
                const int base = rpos * 68 + kk * 32 + q * 8;
                union { uint2 u2[2]; bf16x8 v; } f;
                f.u2[0] = *(const uint2*)(xt + base);
                f.u2[1] = *(const uint2*)(xt + base + 4);
                acc[pt] = __builtin_amdgcn_mfma_f32_16x16x32_bf16(a, f.v, acc[pt], 0, 0, 0);
            }
        }
    }

    #pragma unroll
    for (int pt = 0; pt < 4; ++pt) {
        const int pos = pt * 16 + col;
        if (pos < 49) {
            ushort4 u;
            u.x = f2bf(fmaxf(acc[pt][0] + bv[0], 0.f));
            u.y = f2bf(fmaxf(acc[pt][1] + bv[1], 0.f));
            u.z = f2bf(fmaxf(acc[pt][2] + bv[2], 0.f));
            u.w = f2bf(fmaxf(acc[pt][3] + bv[3], 0.f));
            *(ushort4*)(y + (size_t)b * 3136 + pos * 64 + ot * 16 + q * 4) = u;
        }
    }
}

// ============ fc MFMA: A=a3 bf16 [512,3136] (k'=HWC order), B=wfc [256][3136] -> relu fp32 [512,256]
// wave = 1 mtile x 2 ntiles; grid 64 x 256 (256 waves).
__global__ __launch_bounds__(256) void fc_mfma_k(const ushort* __restrict__ a3,
                                                 const ushort* __restrict__ wfc,
                                                 const float* __restrict__ bias,
                                                 float* __restrict__ feat) {
    const int tid = threadIdx.x;
    const int gw = blockIdx.x * 4 + (tid >> 6);
    const int l = tid & 63, q = l >> 4, col = l & 15;
    const int mtile = gw >> 3, np = gw & 7;

    const ushort* arow = a3 + (size_t)(mtile * 16 + col) * 3136;
    const ushort* brow0 = wfc + (size_t)(np * 32 + col) * 3136;
    const ushort* brow1 = brow0 + (size_t)16 * 3136;

    f32x4 acc0 = {0.f, 0.f, 0.f, 0.f}, acc1 = {0.f, 0.f, 0.f, 0.f};
    #pragma unroll 2
    for (int kk = 0; kk < 98; ++kk) {
        const int ko = kk * 32 + q * 8;
        const bf16x8 av = *(const bf16x8*)(arow + ko);
        const bf16x8 b0 = *(const bf16x8*)(brow0 + ko);
        const bf16x8 b1 = *(const bf16x8*)(brow1 + ko);
        acc0 = __builtin_amdgcn_mfma_f32_16x16x32_bf16(av, b0, acc0, 0, 0, 0);
        acc1 = __builtin_amdgcn_mfma_f32_16x16x32_bf16(av, b1, acc1, 0, 0, 0);
    }

    #pragma unroll
    for (int r = 0; r < 4; ++r) {
        const int m = mtile * 16 + q * 4 + r;
        const int n0 = np * 32 + col, n1 = n0 + 16;
        feat[m * 256 + n0] = fmaxf(acc0[r] + bias[n0], 0.f);
        feat[m * 256 + n1] = fmaxf(acc1[r] + bias[n1], 0.f);
    }
}

// ============ heads (fp32) ============
__global__ __launch_bounds__(256) void dense256_relu_k(const float* __restrict__ in,
                                                       const float* __restrict__ w,
                                                       const float* __restrict__ bias,
                                                       float* __restrict__ out) {
    __shared__ float lin[256];
    const int b = blockIdx.x, tid = threadIdx.x;
    lin[tid] = in[b * 256 + tid];
    __syncthreads();
    float acc = bias[tid];
    #pragma unroll 8
    for (int k = 0; k < 256; ++k) acc += lin[k] * w[k * 256 + tid];
    out[b * 256 + tid] = fmaxf(acc, 0.f);
}

__global__ __launch_bounds__(256) void dense64_k(const float* __restrict__ in,
                                                 const float* __restrict__ w,
                                                 const float* __restrict__ bias,
                                                 float* __restrict__ out) {
    __shared__ float lin[4 * 256];
    const int tid = threadIdx.x;
    const int b0 = blockIdx.x * 4;
    for (int i = tid; i < 1024; i += 256) lin[i] = in[b0 * 256 + i];
    __syncthreads();
    const int r = tid >> 6, n = tid & 63;
    float acc = bias[n];
    #pragma unroll 8
    for (int k = 0; k < 256; ++k) acc += lin[r * 256 + k] * w[k * 64 + n];
    out[(b0 + r) * 64 + n] = acc;
}

__global__ __launch_bounds__(64) void dense1_k(const float* __restrict__ in,
                                               const float* __restrict__ w,
                                               const float* __restrict__ bias,
                                               float* __restrict__ out) {
    const int b = blockIdx.x, l = threadIdx.x;
    const float4 hv = *(const float4*)(in + b * 256 + l * 4);
    const float4 wv = *(const float4*)(w + l * 4);
    float p = hv.x * wv.x + hv.y * wv.y + hv.z * wv.z + hv.w * wv.w;
    #pragma unroll
    for (int off = 32; off > 0; off >>= 1) p += __shfl_down(p, off);
    if (l == 0) out[b] = p + bias[0];
}

__global__ __launch_bounds__(256) void transpose_phi_k(const float* __restrict__ phi,
                                                       float* __restrict__ phiT) {
    const int idx = blockIdx.x * 256 + threadIdx.x;
    const int j = idx >> 6, k = idx & 63;
    phiT[k * 512 + j] = phi[idx];
}

__global__ __launch_bounds__(256) void row_lse_k(const float* __restrict__ phi_x,
                                                 const float* __restrict__ phiYT,
                                                 const float* __restrict__ c_y,
                                                 float* __restrict__ row_lse,
                                                 float* __restrict__ row_diag) {
    const int i = blockIdx.x, tid = threadIdx.x;
    __shared__ float px[64];
    __shared__ float red[256];
    if (tid < 64) px[tid] = phi_x[i * 64 + tid];
    __syncthreads();

    float lg[2];
    #pragma unroll
    for (int q = 0; q < 2; ++q) {
        const int j = tid + q * 256;
        float m = -1e30f;
        #pragma unroll 8
        for (int k = 0; k < 32; ++k) m = fmaxf(m, px[k] - phiYT[k * 512 + j]);
        const float maxc = fmaxf(m, 0.f);
        float s = 0.f;
        #pragma unroll 8
        for (int k = 32; k < 64; ++k) {
            const float d = px[k] - phiYT[k * 512 + j];
            s += d * d;
        }
        lg[q] = c_y[j] - (maxc + sqrtf(s + 1e-8f));
    }
    if ((i & 255) == tid) row_diag[i] = lg[i >> 8];

    red[tid] = fmaxf(lg[0], lg[1]);
    __syncthreads();
    for (int s = 128; s > 0; s >>= 1) {
        if (tid < s) red[tid] = fmaxf(red[tid], red[tid + s]);
        __syncthreads();
    }
    const float m = red[0];
    __syncthreads();
    red[tid] = expf(lg[0] - m) + expf(lg[1] - m);
    __syncthreads();
    for (int s = 128; s > 0; s >>= 1) {
        if (tid < s) red[tid] += red[tid + s];
        __syncthreads();
    }
    if (tid == 0) row_lse[i] = m + logf(red[0]);
}

__global__ __launch_bounds__(512) void loss_k(const float* __restrict__ row_lse,
                                              const float* __restrict__ row_diag,
                                              float* __restrict__ out) {
    __shared__ float r1[512], r2[512];
    const int t = threadIdx.x;
    const float lse = row_lse[t], dg = row_diag[t];
    r1[t] = lse - dg;
    const float l = lse + 1e-6f;
    r2[t] = l * l;
    __syncthreads();
    for (int s = 256; s > 0; s >>= 1) {
        if (t < s) { r1[t] += r1[t + s]; r2[t] += r2[t + s]; }
        __syncthreads();
    }
    if (t == 0) out[0] = r1[0] / 512.f + 0.1f * (r2[0] / 512.f);
}

extern "C" void kernel_launch(void* const* d_in, const int* in_sizes, int n_in,
                              void* d_out, int out_size, void* d_ws, size_t ws_size,
                              hipStream_t stream) {
    const float* curr = (const float*)d_in[0];
    const float* nxt  = (const float*)d_in[1];
    const float* c1w  = (const float*)d_in[2];
    const float* c1b  = (const float*)d_in[3];
    const float* c2w  = (const float*)d_in[4];
    const float* c2b  = (const float*)d_in[5];
    const float* c3w  = (const float*)d_in[6];
    const float* c3b  = (const float*)d_in[7];
    const float* fcw  = (const float*)d_in[8];
    const float* fcb  = (const float*)d_in[9];
    const float* e1w  = (const float*)d_in[10];
    const float* e1b  = (const float*)d_in[11];
    const float* e2w  = (const float*)d_in[12];
    const float* e2b  = (const float*)d_in[13];
    const float* pw1  = (const float*)d_in[14];
    const float* pb1  = (const float*)d_in[15];
    const float* pw2  = (const float*)d_in[16];
    const float* pb2  = (const float*)d_in[17];

    ushort* a1bf = (ushort*)d_ws;                  // 6,553,600
    ushort* a2bf = a1bf + 6553600;                 // 2,654,208
    ushort* a3bf = a2bf + 2654208;                 // 1,605,632
    ushort* wp1  = a3bf + 1605632;                 // 8,192
    ushort* wp2  = wp1 + 8192;                     // 32,768
    ushort* wp3  = wp2 + 32768;                    // 36,864
    ushort* wfc  = wp3 + 36864;                    // 802,816
    float*  feat_c = (float*)(wfc + 802816);       // 131,072
    float*  feat_n = feat_c + 131072;
    float*  h1     = feat_n + 131072;
    float*  phi_x  = h1 + 131072;
    float*  phi_y  = phi_x + 32768;
    float*  phiYT  = phi_y + 32768;
    float*  c_y    = phiYT + 32768;
    float*  rlse   = c_y + 512;
    float*  rdiag  = rlse + 512;

    repack_w1_k<<<32, 256, 0, stream>>>(c1w, wp1);
    repack_w2_k<<<128, 256, 0, stream>>>(c2w, wp2);
    repack_w3_k<<<144, 256, 0, stream>>>(c3w, wp3);
    repack_wfc_k<<<3136, 256, 0, stream>>>(fcw, wfc);

    for (int pass = 0; pass < 2; ++pass) {
        const float* obs = pass ? nxt : curr;
        float* feat = pass ? feat_n : feat_c;
        conv1_mfma_k<<<512, 256, 0, stream>>>(obs, wp1, c1b, a1bf);
        conv2_mfma_k<<<512, 256, 0, stream>>>(a1bf, wp2, c2b, a2bf);
        conv3_mfma_k<<<512, 256, 0, stream>>>(a2bf, wp3, c3b, a3bf);
        fc_mfma_k<<<64, 256, 0, stream>>>(a3bf, wfc, fcb, feat);
    }

    dense256_relu_k<<<512, 256, 0, stream>>>(feat_c, e1w, e1b, h1);
    dense64_k<<<128, 256, 0, stream>>>(h1, e2w, e2b, phi_x);
    dense256_relu_k<<<512, 256, 0, stream>>>(feat_n, e1w, e1b, h1);
    dense64_k<<<128, 256, 0, stream>>>(h1, e2w, e2b, phi_y);
    dense256_relu_k<<<512, 256, 0, stream>>>(feat_n, pw1, pb1, h1);
    dense1_k<<<512, 64, 0, stream>>>(h1, pw2, pb2, c_y);

    transpose_phi_k<<<128, 256, 0, stream>>>(phi_y, phiYT);
    row_lse_k<<<512, 256, 0, stream>>>(phi_x, phiYT, c_y, rlse, rdiag);
    loss_k<<<1, 512, 0, stream>>>(rlse, rdiag, (float*)d_out);
}

// Round 5
// 315.556 us; speedup vs baseline: 6.9497x; 1.2192x over previous
//
#include <hip/hip_runtime.h>
#include <math.h>

typedef __attribute__((ext_vector_type(8))) short bf16x8;
typedef __attribute__((ext_vector_type(4))) float f32x4;

static __device__ __forceinline__ ushort f2bf(float x) {
    union { float f; unsigned u; } a; a.f = x;
    unsigned r = a.u + 0x7fff + ((a.u >> 16) & 1);   // RNE
    return (ushort)(r >> 16);
}

// ============ fused weight repack (bf16, MFMA A-fragment order) ============
// block ranges: [0,32) wp1, [32,160) wp2, [160,304) wp3, [304,3440) wfc
__global__ __launch_bounds__(256) void repack_all_k(const float* __restrict__ c1w,
                                                    const float* __restrict__ c2w,
                                                    const float* __restrict__ c3w,
                                                    const float* __restrict__ fcw,
                                                    ushort* __restrict__ wp1,
                                                    ushort* __restrict__ wp2,
                                                    ushort* __restrict__ wp3,
                                                    ushort* __restrict__ wfc) {
    const int blk = blockIdx.x;
    if (blk < 32) {                       // conv1 w [32][256]
        const int t = blk * 256 + threadIdx.x;
        const int j = t & 7, l = (t >> 3) & 63, kk = (t >> 9) & 7, ot = t >> 12;
        const int oc = ot * 16 + (l & 15);
        const int k  = kk * 32 + ((l >> 4) * 8) + j;
        wp1[t] = f2bf(c1w[oc * 256 + k]);
    } else if (blk < 160) {               // conv2 w [64][512]
        const int t = (blk - 32) * 256 + threadIdx.x;
        const int j = t & 7, l = (t >> 3) & 63, kk = (t >> 9) & 15, wv = t >> 13;
        const int oc = wv * 16 + (l & 15);
        const int k  = kk * 32 + ((l >> 4) * 8) + j;
        wp2[t] = f2bf(c2w[oc * 512 + k]);
    } else if (blk < 304) {               // conv3 w [64][64][9] per kp
        const int t = (blk - 160) * 256 + threadIdx.x;
        const int j = t & 7, l = (t >> 3) & 63, kk = (t >> 9) & 1;
        const int ot = (t >> 10) & 3, kp = t >> 12;
        const int oc = ot * 16 + (l & 15);
        const int ic = kk * 32 + ((l >> 4) * 8) + j;
        wp3[t] = f2bf(c3w[(oc * 64 + ic) * 9 + kp]);
    } else {                              // fc w [3136][256] -> [n][k'=pos*64+oc]
        const int t = (blk - 304) * 256 + threadIdx.x;
        const int n = t / 3136, kp = t % 3136;
        const int pos = kp >> 6, oc = kp & 63;
        wfc[t] = f2bf(fcw[(oc * 49 + pos) * 256 + n]);
    }
}

// ============ conv1 MFMA: fp32 [2x512,4,84,84] * [32,4,8,8] s4 -> relu -> bf16 CHW [2x512,32,400]
// grid 2048: pass x image x oh-supertile. 44 input rows staged (29.6 KB LDS).
__global__ __launch_bounds__(256) void conv1_mfma_k(const float* __restrict__ curr,
                                                    const float* __restrict__ nxt,
                                                    const ushort* __restrict__ wpack,
                                                    const float* __restrict__ bias,
                                                    ushort* __restrict__ y) {
    __shared__ ushort xt[4 * 44 * 84];   // 14784
    const int tid = threadIdx.x;
    const int pass = blockIdx.x >> 10;
    const int rb = blockIdx.x & 1023;
    const int b = rb >> 1, sup = rb & 1;

    const float* xb = (pass ? nxt : curr) + (size_t)b * 28224;
    const int ih0 = sup * 40;
    for (int i = tid; i < 3696; i += 256) {   // 44*21 float4 per ch * 4ch
        const int row = i / 21, col = i % 21;
        const int ic = row / 44, rr = row % 44;
        const float4 v = *(const float4*)(xb + ic * 7056 + (ih0 + rr) * 84 + col * 4);
        ushort4 u; u.x = f2bf(v.x); u.y = f2bf(v.y); u.z = f2bf(v.z); u.w = f2bf(v.w);
        *(ushort4*)(xt + (ic * 44 + rr) * 84 + col * 4) = u;
    }
    __syncthreads();

    const int wv = tid >> 6, l = tid & 63, q = l >> 4, col = l & 15;

    bf16x8 a[2][8];
    const bf16x8* wp = (const bf16x8*)wpack;
    #pragma unroll
    for (int ot = 0; ot < 2; ++ot)
        #pragma unroll
        for (int kk = 0; kk < 8; ++kk) a[ot][kk] = wp[(ot * 8 + kk) * 64 + l];

    float bv[2][4];
    #pragma unroll
    for (int ot = 0; ot < 2; ++ot)
        #pragma unroll
        for (int r = 0; r < 4; ++r) bv[ot][r] = bias[ot * 16 + q * 4 + r];

    const size_t ybase = ((size_t)(pass * 512 + b)) * 32 * 400;

    for (int t = wv; t < 13; t += 4) {
        const int lraw = t * 16 + col;          // < 208
        const int lpos = lraw < 200 ? lraw : 199;
        const int ohl = lpos / 20, ow = lpos % 20;
        f32x4 acc0 = {0.f, 0.f, 0.f, 0.f}, acc1 = {0.f, 0.f, 0.f, 0.f};
        #pragma unroll
        for (int kk = 0; kk < 8; ++kk) {
            const int ickh = kk * 4 + q;
            const int ic = ickh >> 3, kh = ickh & 7;
            const int base = ic * 3696 + (ohl * 4 + kh) * 84 + ow * 4;
            union { uint2 u2[2]; bf16x8 v; } f;
            f.u2[0] = *(const uint2*)(xt + base);
            f.u2[1] = *(const uint2*)(xt + base + 4);
            acc0 = __builtin_amdgcn_mfma_f32_16x16x32_bf16(a[0][kk], f.v, acc0, 0, 0, 0);
            acc1 = __builtin_amdgcn_mfma_f32_16x16x32_bf16(a[1][kk], f.v, acc1, 0, 0, 0);
        }
        if (lraw < 200) {
            const int pos = sup * 200 + lraw;
            #pragma unroll
            for (int r = 0; r < 4; ++r) {
                y[ybase + (size_t)(q * 4 + r) * 400 + pos]      = f2bf(fmaxf(acc0[r] + bv[0][r], 0.f));
                y[ybase + (size_t)(16 + q * 4 + r) * 400 + pos] = f2bf(fmaxf(acc1[r] + bv[1][r], 0.f));
            }
        }
    }
}

// ============ fused conv2+conv3: bf16 CHW [.,32,20,20] -> (LDS HWC 81x64) -> bf16 HWC [.,49,64]
__global__ __launch_bounds__(256) void conv23_mfma_k(const ushort* __restrict__ x,
                                                     const ushort* __restrict__ wp2g,
                                                     const float* __restrict__ b2,
                                                     const ushort* __restrict__ wp3g,
                                                     const float* __restrict__ b3,
                                                     ushort* __restrict__ y) {
    __shared__ ushort xt[12800];      // conv2 input  25.6 KB
    __shared__ ushort xt2[81 * 68];   // conv2 output 11.0 KB (pitch 68)
    const int tid = threadIdx.x;
    const int img = blockIdx.x;       // 0..1023 (pass*512+b)

    const uint4* xg = (const uint4*)(x + (size_t)img * 12800);
    for (int i = tid; i < 1600; i += 256) *(uint4*)(xt + i * 8) = xg[i];
    __syncthreads();

    const int wv = tid >> 6, l = tid & 63, quad = l >> 4, col = l & 15;

    // ---- conv2 ----
    {
        int ohs[6], ows[6];
        #pragma unroll
        for (int t = 0; t < 6; ++t) {
            int pos = t * 16 + col; if (pos > 80) pos = 80;
            ohs[t] = pos / 9; ows[t] = pos % 9;
        }
        const int ic_off = quad >> 1;
        const int kh2    = (quad & 1) * 2;

        float bias_v[4];
        #pragma unroll
        for (int r2 = 0; r2 < 4; ++r2) bias_v[r2] = b2[wv * 16 + quad * 4 + r2];

        f32x4 acc[6];
        #pragma unroll
        for (int t = 0; t < 6; ++t) acc[t] = (f32x4){0.f, 0.f, 0.f, 0.f};

        const bf16x8* wp = (const bf16x8*)wp2g;
        for (int kk = 0; kk < 16; ++kk) {
            const bf16x8 a = wp[(wv * 16 + kk) * 64 + l];
            const int ic = kk * 2 + ic_off;
            #pragma unroll
            for (int t = 0; t < 6; ++t) {
                const int base = ic * 400 + (ohs[t] * 2 + kh2) * 20 + ows[t] * 2;
                const unsigned* p0 = (const unsigned*)(xt + base);
                const unsigned* p1 = (const unsigned*)(xt + base + 20);
                union { unsigned u[4]; bf16x8 v; } f;
                f.u[0] = p0[0]; f.u[1] = p0[1];
                f.u[2] = p1[0]; f.u[3] = p1[1];
                acc[t] = __builtin_amdgcn_mfma_f32_16x16x32_bf16(a, f.v, acc[t], 0, 0, 0);
            }
        }
        #pragma unroll
        for (int t = 0; t < 6; ++t) {
            const int pos = t * 16 + col;
            if (pos < 81) {
                ushort4 u;
                u.x = f2bf(fmaxf(acc[t][0] + bias_v[0], 0.f));
                u.y = f2bf(fmaxf(acc[t][1] + bias_v[1], 0.f));
                u.z = f2bf(fmaxf(acc[t][2] + bias_v[2], 0.f));
                u.w = f2bf(fmaxf(acc[t][3] + bias_v[3], 0.f));
                *(ushort4*)(xt2 + pos * 68 + wv * 16 + quad * 4) = u;
            }
        }
    }
    __syncthreads();

    // ---- conv3 (9 shifted 1x1 GEMMs over xt2) ----
    {
        int ohs[4], ows[4];
        #pragma unroll
        for (int pt = 0; pt < 4; ++pt) {
            int pos = pt * 16 + col; if (pos > 48) pos = 48;
            ohs[pt] = pos / 7; ows[pt] = pos % 7;
        }
        float bv[4];
        #pragma unroll
        for (int r = 0; r < 4; ++r) bv[r] = b3[wv * 16 + quad * 4 + r];

        f32x4 acc[4];
        #pragma unroll
        for (int pt = 0; pt < 4; ++pt) acc[pt] = (f32x4){0.f, 0.f, 0.f, 0.f};

        const bf16x8* wp = (const bf16x8*)wp3g;
        #pragma unroll
        for (int kp = 0; kp < 9; ++kp) {
            const int kh = kp / 3, kw = kp % 3;
            #pragma unroll
            for (int kk = 0; kk < 2; ++kk) {
                const bf16x8 a = wp[((kp * 4 + wv) * 2 + kk) * 64 + l];
                #pragma unroll
                for (int pt = 0; pt < 4; ++pt) {
                    const int rpos = (ohs[pt] + kh) * 9 + (ows[pt] + kw);
                    const int base = rpos * 68 + kk * 32 + quad * 8;
                    union { uint2 u2[2]; bf16x8 v; } f;
                    f.u2[0] = *(const uint2*)(xt2 + base);
                    f.u2[1] = *(const uint2*)(xt2 + base + 4);
                    acc[pt] = __builtin_amdgcn_mfma_f32_16x16x32_bf16(a, f.v, acc[pt], 0, 0, 0);
                }
            }
        }
        #pragma unroll
        for (int pt = 0; pt < 4; ++pt) {
            const int pos = pt * 16 + col;
            if (pos < 49) {
                ushort4 u;
                u.x = f2bf(fmaxf(acc[pt][0] + bv[0], 0.f));
                u.y = f2bf(fmaxf(acc[pt][1] + bv[1], 0.f));
                u.z = f2bf(fmaxf(acc[pt][2] + bv[2], 0.f));
                u.w = f2bf(fmaxf(acc[pt][3] + bv[3], 0.f));
                *(ushort4*)(y + (size_t)img * 3136 + pos * 64 + wv * 16 + quad * 4) = u;
            }
        }
    }
}

// ============ fc MFMA: [2x512,3136]bf16 @ wfc[256][3136] -> relu fp32 [2x512,256]
__global__ __launch_bounds__(256) void fc_mfma_k(const ushort* __restrict__ a3,
                                                 const ushort* __restrict__ wfc,
                                                 const float* __restrict__ bias,
                                                 float* __restrict__ feat) {
    const int tid = threadIdx.x;
    const int pass = blockIdx.x >> 6;
    const int gw = (blockIdx.x & 63) * 4 + (tid >> 6);
    const int l = tid & 63, q = l >> 4, col = l & 15;
    const int mtile = gw >> 3, np = gw & 7;

    const ushort* arow = a3 + (size_t)pass * 1605632 + (size_t)(mtile * 16 + col) * 3136;
    const ushort* brow0 = wfc + (size_t)(np * 32 + col) * 3136;
    const ushort* brow1 = brow0 + (size_t)16 * 3136;

    f32x4 acc0 = {0.f, 0.f, 0.f, 0.f}, acc1 = {0.f, 0.f, 0.f, 0.f};
    #pragma unroll 2
    for (int kk = 0; kk < 98; ++kk) {
        const int ko = kk * 32 + q * 8;
        const bf16x8 av = *(const bf16x8*)(arow + ko);
        const bf16x8 b0 = *(const bf16x8*)(brow0 + ko);
        const bf16x8 b1 = *(const bf16x8*)(brow1 + ko);
        acc0 = __builtin_amdgcn_mfma_f32_16x16x32_bf16(av, b0, acc0, 0, 0, 0);
        acc1 = __builtin_amdgcn_mfma_f32_16x16x32_bf16(av, b1, acc1, 0, 0, 0);
    }

    float* fb = feat + (size_t)pass * 131072;
    #pragma unroll
    for (int r = 0; r < 4; ++r) {
        const int m = mtile * 16 + q * 4 + r;
        const int n0 = np * 32 + col, n1 = n0 + 16;
        fb[m * 256 + n0] = fmaxf(acc0[r] + bias[n0], 0.f);
        fb[m * 256 + n1] = fmaxf(acc1[r] + bias[n1], 0.f);
    }
}

// ============ fused heads: feat[2][512][256] -> phi_x[512,64], phiYT[64,512], c_y[512]
// grid 256, 2 rows per block. Also zeroes loss accumulators (block 0).
__global__ __launch_bounds__(256) void heads_k(const float* __restrict__ feat,
                                               const float* __restrict__ e1w,
                                               const float* __restrict__ e1b,
                                               const float* __restrict__ e2w,
                                               const float* __restrict__ e2b,
                                               const float* __restrict__ pw1,
                                               const float* __restrict__ pb1,
                                               const float* __restrict__ pw2,
                                               const float* __restrict__ pb2,
                                               float* __restrict__ phi_x,
                                               float* __restrict__ phiYT,
                                               float* __restrict__ c_y,
                                               float* __restrict__ accbuf) {
    __shared__ float fc[2][256], fn[2][256];
    __shared__ float h1c[2][256], h1n[2][256], hp[2][256];
    const int tid = threadIdx.x;
    const int b0 = blockIdx.x * 2;

    if (blockIdx.x == 0 && tid < 4) accbuf[tid] = 0.f;

    for (int i = tid; i < 512; i += 256) {
        const int rr = i >> 8, c = i & 255;
        fc[rr][c] = feat[(b0 + rr) * 256 + c];
        fn[rr][c] = feat[131072 + (b0 + rr) * 256 + c];
    }
    __syncthreads();

    // phase 1: h1 = relu(f @ e1w + e1b), hp = relu(fn @ pw1 + pb1)
    float ac0 = e1b[tid], ac1 = ac0;
    float an0 = ac0, an1 = ac0;
    float ap0 = pb1[tid], ap1 = ap0;
    for (int k = 0; k < 256; ++k) {
        const float we = e1w[k * 256 + tid];
        const float wpv = pw1[k * 256 + tid];
        ac0 += fc[0][k] * we;  ac1 += fc[1][k] * we;
        an0 += fn[0][k] * we;  an1 += fn[1][k] * we;
        ap0 += fn[0][k] * wpv; ap1 += fn[1][k] * wpv;
    }
    h1c[0][tid] = fmaxf(ac0, 0.f); h1c[1][tid] = fmaxf(ac1, 0.f);
    h1n[0][tid] = fmaxf(an0, 0.f); h1n[1][tid] = fmaxf(an1, 0.f);
    hp[0][tid]  = fmaxf(ap0, 0.f); hp[1][tid]  = fmaxf(ap1, 0.f);
    __syncthreads();

    // phase 2
    const int wave = tid >> 6, lane = tid & 63;
    if (wave == 0) {                 // phi_x
        #pragma unroll
        for (int rr = 0; rr < 2; ++rr) {
            float s = e2b[lane];
            for (int k = 0; k < 256; ++k) s += h1c[rr][k] * e2w[k * 64 + lane];
            phi_x[(b0 + rr) * 64 + lane] = s;
        }
    } else if (wave == 1) {          // phi_y (written transposed)
        #pragma unroll
        for (int rr = 0; rr < 2; ++rr) {
            float s = e2b[lane];
            for (int k = 0; k < 256; ++k) s += h1n[rr][k] * e2w[k * 64 + lane];
            phiYT[lane * 512 + b0 + rr] = s;
        }
    } else {                         // c_y, one wave per row
        const int rr = wave - 2;
        float s = 0.f;
        #pragma unroll
        for (int q2 = 0; q2 < 4; ++q2) s += hp[rr][lane * 4 + q2] * pw2[lane * 4 + q2];
        #pragma unroll
        for (int off = 32; off > 0; off >>= 1) s += __shfl_down(s, off);
        if (lane == 0) c_y[b0 + rr] = s + pb2[0];
    }
}

// ============ row logits+LSE, fused final loss via atomics
__global__ __launch_bounds__(256) void row_lse_loss_k(const float* __restrict__ phi_x,
                                                      const float* __restrict__ phiYT,
                                                      const float* __restrict__ c_y,
                                                      float* __restrict__ accbuf,
                                                      float* __restrict__ out) {
    const int i = blockIdx.x, tid = threadIdx.x;
    __shared__ float px[64];
    __shared__ float red[256];
    __shared__ float sdiag;
    if (tid < 64) px[tid] = phi_x[i * 64 + tid];
    __syncthreads();

    float lg[2];
    #pragma unroll
    for (int q = 0; q < 2; ++q) {
        const int j = tid + q * 256;
        float m = -1e30f;
        #pragma unroll 8
        for (int k = 0; k < 32; ++k) m = fmaxf(m, px[k] - phiYT[k * 512 + j]);
        const float maxc = fmaxf(m, 0.f);
        float s = 0.f;
        #pragma unroll 8
        for (int k = 32; k < 64; ++k) {
            const float d = px[k] - phiYT[k * 512 + j];
            s += d * d;
        }
        lg[q] = c_y[j] - (maxc + sqrtf(s + 1e-8f));
    }
    if ((i & 255) == tid) sdiag = lg[i >> 8];

    red[tid] = fmaxf(lg[0], lg[1]);
    __syncthreads();
    for (int s = 128; s > 0; s >>= 1) {
        if (tid < s) red[tid] = fmaxf(red[tid], red[tid + s]);
        __syncthreads();
    }
    const float m = red[0];
    __syncthreads();
    red[tid] = expf(lg[0] - m) + expf(lg[1] - m);
    __syncthreads();
    for (int s = 128; s > 0; s >>= 1) {
        if (tid < s) red[tid] += red[tid + s];
        __syncthreads();
    }

    if (tid == 0) {
        const float lse = m + logf(red[0]);
        const float l2 = lse + 1e-6f;
        atomicAdd(&accbuf[0], lse - sdiag);
        atomicAdd(&accbuf[1], l2 * l2);
        __threadfence();
        const unsigned old = atomicAdd((unsigned*)&accbuf[2], 1u);
        if (old == 511u) {
            __threadfence();
            const float s1 = atomicAdd(&accbuf[0], 0.f);
            const float s2 = atomicAdd(&accbuf[1], 0.f);
            out[0] = s1 / 512.f + 0.1f * (s2 / 512.f);
        }
    }
}

extern "C" void kernel_launch(void* const* d_in, const int* in_sizes, int n_in,
                              void* d_out, int out_size, void* d_ws, size_t ws_size,
                              hipStream_t stream) {
    const float* curr = (const float*)d_in[0];
    const float* nxt  = (const float*)d_in[1];
    const float* c1w  = (const float*)d_in[2];
    const float* c1b  = (const float*)d_in[3];
    const float* c2w  = (const float*)d_in[4];
    const float* c2b  = (const float*)d_in[5];
    const float* c3w  = (const float*)d_in[6];
    const float* c3b  = (const float*)d_in[7];
    const float* fcw  = (const float*)d_in[8];
    const float* fcb  = (const float*)d_in[9];
    const float* e1w  = (const float*)d_in[10];
    const float* e1b  = (const float*)d_in[11];
    const float* e2w  = (const float*)d_in[12];
    const float* e2b  = (const float*)d_in[13];
    const float* pw1  = (const float*)d_in[14];
    const float* pb1  = (const float*)d_in[15];
    const float* pw2  = (const float*)d_in[16];
    const float* pb2  = (const float*)d_in[17];

    ushort* a1  = (ushort*)d_ws;                   // 2 x 6,553,600 = 13,107,200
    ushort* a3  = a1 + 13107200;                   // 2 x 1,605,632 = 3,211,264
    ushort* wp1 = a3 + 3211264;                    // 8,192
    ushort* wp2 = wp1 + 8192;                      // 32,768
    ushort* wp3 = wp2 + 32768;                     // 36,864
    ushort* wfc = wp3 + 36864;                     // 802,816
    float*  feat  = (float*)(wfc + 802816);        // 2 x 131,072
    float*  phi_x = feat + 262144;                 // 32,768
    float*  phiYT = phi_x + 32768;                 // 32,768
    float*  c_y   = phiYT + 32768;                 // 512
    float*  acc   = c_y + 512;                     // 4

    repack_all_k<<<3440, 256, 0, stream>>>(c1w, c2w, c3w, fcw, wp1, wp2, wp3, wfc);
    conv1_mfma_k<<<2048, 256, 0, stream>>>(curr, nxt, wp1, c1b, a1);
    conv23_mfma_k<<<1024, 256, 0, stream>>>(a1, wp2, c2b, wp3, c3b, a3);
    fc_mfma_k<<<128, 256, 0, stream>>>(a3, wfc, fcb, feat);
    heads_k<<<256, 256, 0, stream>>>(feat, e1w, e1b, e2w, e2b, pw1, pb1, pw2, pb2,
                                     phi_x, phiYT, c_y, acc);
    row_lse_loss_k<<<512, 256, 0, stream>>>(phi_x, phiYT, c_y, acc, (float*)d_out);
}